// Round 3
// baseline (772.111 us; speedup 1.0000x reference)
//
#include <hip/hip_runtime.h>
#include <hip/hip_bf16.h>

// ---------------- problem constants (layer_idx==1 fixed by setup_inputs) ----
#define BATCHN 2
#define SEQ    2048
#define HID    1024
#define NHEADS 16
#define HD     64
#define P_LO   478     // _sample_indices(1) -> p=478, q=785
#define NF     307     // q - p
#define NF2    614     // cos rows + sin rows
#define NFP    640     // padded to multiple of 64 (rows 614..639 zero)
#define KTOP   15      // int(2*log(2049)) = 15
#define DPI    3.14159265358979323846

typedef __bf16 bf16_t;
typedef bf16_t v8bf __attribute__((ext_vector_type(8)));
typedef float  v4f  __attribute__((ext_vector_type(4)));
typedef float  v4fx __attribute__((ext_vector_type(4)));

#define MFMA(a,b,c) __builtin_amdgcn_mfma_f32_16x16x32_bf16(a,b,c,0,0,0)
// A-frag: m=lane&15, k=(lane>>4)*8+j ; B-frag: n=lane&15, k=(lane>>4)*8+j
// C/D   : col(n)=lane&15, row(m)=(lane>>4)*4+reg   [m89/m120 verified]

#define TBK 32
#define TKP 40   // padded LDS leading dim (80 B stride, 16 B aligned)

// ---------------- dtype detector --------------------------------------------
// bf16 N(0,1)/0.02-scale data: exponent field < 0x90 always. float32 data read
// as bf16 halves: ~44% of low halves have exponent >= 0x90. flag: 0=bf16 1=f32
__launch_bounds__(256)
__global__ void detect_kernel(const unsigned short* __restrict__ x0,
                              const unsigned short* __restrict__ x1,
                              int* __restrict__ flag) {
    int t = threadIdx.x, bad = 0;
    for (int i = t; i < 8192; i += 256) {
        unsigned e0 = (x0[i] >> 7) & 0xFF; if (e0 >= 0x90) bad++;
        unsigned e1 = (x1[i] >> 7) & 0xFF; if (e1 >= 0x90) bad++;
    }
    __shared__ int s[256];
    s[t] = bad; __syncthreads();
    for (int st = 128; st; st >>= 1) { if (t < st) s[t] += s[t + st]; __syncthreads(); }
    if (t == 0) *flag = (s[0] > 64) ? 1 : 0;
}

// ---------------- table generation (dtype-independent) ----------------------
__launch_bounds__(256)
__global__ void tab_band_kernel(bf16_t* __restrict__ Ahi, bf16_t* __restrict__ Alo) {
    int m = blockIdx.x * 256 + threadIdx.x;
    int r = blockIdx.y;
    double v = 0.0;
    if (r < NF2) {
        int f  = P_LO + (r < NF ? r : r - NF);
        int ph = (f * m) & (SEQ - 1);
        double ang = (2.0 * DPI / SEQ) * (double)ph;
        v = (r < NF) ? cos(ang) : sin(ang);
    }
    bf16_t h = (bf16_t)(float)v;
    float  res = (float)(v - (double)(float)h);
    Ahi[(size_t)r * SEQ + m] = h;
    Alo[(size_t)r * SEQ + m] = (bf16_t)res;
}

__launch_bounds__(128)
__global__ void tab_inv_kernel(bf16_t* __restrict__ Gt) {
    int r = blockIdx.x * 128 + threadIdx.x;
    int n = blockIdx.y;
    float v = 0.f;
    if (r < NF2) {
        int f  = P_LO + (r < NF ? r : r - NF);
        int ph = (f * n) & (SEQ - 1);
        double ang = (2.0 * DPI / SEQ) * (double)ph;
        v = (float)((2.0 / SEQ) * ((r < NF) ? cos(ang) : sin(ang)));
    }
    Gt[(size_t)n * NFP + r] = (bf16_t)v;
}

// ---------------- staging helpers -------------------------------------------
template<typename T>
__device__ __forceinline__ void load8(const T* p, float (&x)[8]) {
    if constexpr (__is_same(T, float)) {
        v4fx a = *(const v4fx*)p, b = *(const v4fx*)(p + 4);
        #pragma unroll
        for (int e = 0; e < 4; e++) { x[e] = a[e]; x[4 + e] = b[e]; }
    } else {
        v8bf a = *(const v8bf*)p;
        #pragma unroll
        for (int e = 0; e < 8; e++) x[e] = (float)a[e];
    }
}

// ---------------- GEMM NT: C[M,1024] = A[M,K] @ B[1024,K]^T + bias ----------
template<typename AT, typename BT, typename OT>
__launch_bounds__(256)
__global__ void gemm_nt_kernel(const int* __restrict__ flag, int want,
                               const AT* __restrict__ A, const BT* __restrict__ Bm,
                               const BT* __restrict__ bias, OT* __restrict__ C, int K) {
    if (*flag != want) return;
    __shared__ __align__(16) bf16_t As[64 * TKP];
    __shared__ __align__(16) bf16_t Bs[64 * TKP];
    int t = threadIdx.x, wave = t >> 6, lane = t & 63;
    int lrow = lane & 15, quad = lane >> 4;
    int m0 = blockIdx.y * 64, n0 = blockIdx.x * 64;
    int wm = (wave >> 1) * 32, wn = (wave & 1) * 32;
    int srow = t >> 2, scol = (t & 3) * 8;
    v4f acc[2][2] = {};
    for (int k0 = 0; k0 < K; k0 += TBK) {
        __syncthreads();
        float xa[8], xb[8];
        load8(&A[(size_t)(m0 + srow) * K + k0 + scol], xa);
        load8(&Bm[(size_t)(n0 + srow) * K + k0 + scol], xb);
        #pragma unroll
        for (int e = 0; e < 8; e++) {
            As[srow * TKP + scol + e] = (bf16_t)xa[e];
            Bs[srow * TKP + scol + e] = (bf16_t)xb[e];
        }
        __syncthreads();
        v8bf a0 = *(v8bf*)&As[(wm + lrow) * TKP + quad * 8];
        v8bf a1 = *(v8bf*)&As[(wm + 16 + lrow) * TKP + quad * 8];
        v8bf b0 = *(v8bf*)&Bs[(wn + lrow) * TKP + quad * 8];
        v8bf b1 = *(v8bf*)&Bs[(wn + 16 + lrow) * TKP + quad * 8];
        acc[0][0] = MFMA(a0, b0, acc[0][0]);
        acc[0][1] = MFMA(a0, b1, acc[0][1]);
        acc[1][0] = MFMA(a1, b0, acc[1][0]);
        acc[1][1] = MFMA(a1, b1, acc[1][1]);
    }
    #pragma unroll
    for (int i = 0; i < 2; i++)
    #pragma unroll
    for (int j = 0; j < 2; j++) {
        int col = n0 + wn + 16 * j + lrow;
        float bvv = (float)bias[col];
        #pragma unroll
        for (int rg = 0; rg < 4; rg++) {
            int row = m0 + wm + 16 * i + quad * 4 + rg;
            C[(size_t)row * HID + col] = (OT)(acc[i][j][rg] + bvv);
        }
    }
}

// ---------------- band forward: Xf[b,r,d] = sum_m A[r,m] X[b,m,d] -----------
// A split hi/lo always; B (=X) split when IT=float. Output split hi/lo bf16.
template<typename IT, bool SPLITB>
__launch_bounds__(256)
__global__ void band_fwd_kernel(const int* __restrict__ flag, int want,
                                const bf16_t* __restrict__ Ahi, const bf16_t* __restrict__ Alo,
                                const IT* __restrict__ X,
                                bf16_t* __restrict__ Xfh, bf16_t* __restrict__ Xfl) {
    if (*flag != want) return;
    __shared__ __align__(16) bf16_t Ash[64 * TKP];
    __shared__ __align__(16) bf16_t Asl[64 * TKP];
    __shared__ __align__(16) bf16_t Bsh[64 * TKP];
    __shared__ __align__(16) bf16_t Bsl[SPLITB ? 64 * TKP : 8];
    const IT* Bp = X + (size_t)blockIdx.z * SEQ * HID;
    int t = threadIdx.x, wave = t >> 6, lane = t & 63;
    int lrow = lane & 15, quad = lane >> 4;
    int m0 = blockIdx.y * 64, n0 = blockIdx.x * 64;
    int wm = (wave >> 1) * 32, wn = (wave & 1) * 32;
    int srow = t >> 2, scol = (t & 3) * 8;
    int brow = t >> 3, bcol = (t & 7) * 8;
    v4f acc[2][2] = {};
    for (int k0 = 0; k0 < SEQ; k0 += TBK) {
        __syncthreads();
        *(v8bf*)&Ash[srow * TKP + scol] = *(const v8bf*)&Ahi[(size_t)(m0 + srow) * SEQ + k0 + scol];
        *(v8bf*)&Asl[srow * TKP + scol] = *(const v8bf*)&Alo[(size_t)(m0 + srow) * SEQ + k0 + scol];
        {
            float bx[8];
            load8(&Bp[(size_t)(k0 + brow) * HID + n0 + bcol], bx);
            #pragma unroll
            for (int e = 0; e < 8; e++) {
                bf16_t h = (bf16_t)bx[e];
                Bsh[(bcol + e) * TKP + brow] = h;
                if constexpr (SPLITB) Bsl[(bcol + e) * TKP + brow] = (bf16_t)(bx[e] - (float)h);
            }
        }
        __syncthreads();
        v8bf b0 = *(v8bf*)&Bsh[(wn + lrow) * TKP + quad * 8];
        v8bf b1 = *(v8bf*)&Bsh[(wn + 16 + lrow) * TKP + quad * 8];
        v8bf ah0 = *(v8bf*)&Ash[(wm + lrow) * TKP + quad * 8];
        v8bf ah1 = *(v8bf*)&Ash[(wm + 16 + lrow) * TKP + quad * 8];
        v8bf al0 = *(v8bf*)&Asl[(wm + lrow) * TKP + quad * 8];
        v8bf al1 = *(v8bf*)&Asl[(wm + 16 + lrow) * TKP + quad * 8];
        acc[0][0] = MFMA(ah0, b0, acc[0][0]);  acc[0][0] = MFMA(al0, b0, acc[0][0]);
        acc[0][1] = MFMA(ah0, b1, acc[0][1]);  acc[0][1] = MFMA(al0, b1, acc[0][1]);
        acc[1][0] = MFMA(ah1, b0, acc[1][0]);  acc[1][0] = MFMA(al1, b0, acc[1][0]);
        acc[1][1] = MFMA(ah1, b1, acc[1][1]);  acc[1][1] = MFMA(al1, b1, acc[1][1]);
        if constexpr (SPLITB) {
            v8bf bl0 = *(v8bf*)&Bsl[(wn + lrow) * TKP + quad * 8];
            v8bf bl1 = *(v8bf*)&Bsl[(wn + 16 + lrow) * TKP + quad * 8];
            acc[0][0] = MFMA(ah0, bl0, acc[0][0]);
            acc[0][1] = MFMA(ah0, bl1, acc[0][1]);
            acc[1][0] = MFMA(ah1, bl0, acc[1][0]);
            acc[1][1] = MFMA(ah1, bl1, acc[1][1]);
        }
    }
    bf16_t* oh = Xfh + (size_t)blockIdx.z * NFP * HID;
    bf16_t* ol = Xfl + (size_t)blockIdx.z * NFP * HID;
    #pragma unroll
    for (int i = 0; i < 2; i++)
    #pragma unroll
    for (int j = 0; j < 2; j++) {
        int col = n0 + wn + 16 * j + lrow;
        #pragma unroll
        for (int rg = 0; rg < 4; rg++) {
            int row = m0 + wm + 16 * i + quad * 4 + rg;
            float v = acc[i][j][rg];
            bf16_t h = (bf16_t)v;
            oh[(size_t)row * HID + col] = h;
            ol[(size_t)row * HID + col] = (bf16_t)(v - (float)h);
        }
    }
}

// ---------------- proj: Qf[b,r,j] = sum_e Xf[b,r,e] W[j,e]  (NT) ------------
// A = Xf split (always). B = W, split when IT=float. No bias (band has no DC).
template<typename IT, bool SPLITB, bool WLO>
__launch_bounds__(256)
__global__ void proj_f_kernel(const int* __restrict__ flag, int want,
                              const bf16_t* __restrict__ Xfh, const bf16_t* __restrict__ Xfl,
                              const IT* __restrict__ W,
                              bf16_t* __restrict__ Ch, bf16_t* __restrict__ Cl) {
    if (*flag != want) return;
    __shared__ __align__(16) bf16_t Ash[64 * TKP];
    __shared__ __align__(16) bf16_t Asl[64 * TKP];
    __shared__ __align__(16) bf16_t Bsh[64 * TKP];
    __shared__ __align__(16) bf16_t Bsl[SPLITB ? 64 * TKP : 8];
    const size_t zo = (size_t)blockIdx.z * NFP * HID;
    int t = threadIdx.x, wave = t >> 6, lane = t & 63;
    int lrow = lane & 15, quad = lane >> 4;
    int m0 = blockIdx.y * 64, n0 = blockIdx.x * 64;
    int wm = (wave >> 1) * 32, wn = (wave & 1) * 32;
    int srow = t >> 2, scol = (t & 3) * 8;
    v4f acc[2][2] = {};
    for (int k0 = 0; k0 < HID; k0 += TBK) {
        __syncthreads();
        *(v8bf*)&Ash[srow * TKP + scol] = *(const v8bf*)&Xfh[zo + (size_t)(m0 + srow) * HID + k0 + scol];
        *(v8bf*)&Asl[srow * TKP + scol] = *(const v8bf*)&Xfl[zo + (size_t)(m0 + srow) * HID + k0 + scol];
        {
            float bx[8];
            load8(&W[(size_t)(n0 + srow) * HID + k0 + scol], bx);
            #pragma unroll
            for (int e = 0; e < 8; e++) {
                bf16_t h = (bf16_t)bx[e];
                Bsh[srow * TKP + scol + e] = h;
                if constexpr (SPLITB) Bsl[srow * TKP + scol + e] = (bf16_t)(bx[e] - (float)h);
            }
        }
        __syncthreads();
        v8bf b0 = *(v8bf*)&Bsh[(wn + lrow) * TKP + quad * 8];
        v8bf b1 = *(v8bf*)&Bsh[(wn + 16 + lrow) * TKP + quad * 8];
        v8bf ah0 = *(v8bf*)&Ash[(wm + lrow) * TKP + quad * 8];
        v8bf ah1 = *(v8bf*)&Ash[(wm + 16 + lrow) * TKP + quad * 8];
        v8bf al0 = *(v8bf*)&Asl[(wm + lrow) * TKP + quad * 8];
        v8bf al1 = *(v8bf*)&Asl[(wm + 16 + lrow) * TKP + quad * 8];
        acc[0][0] = MFMA(ah0, b0, acc[0][0]);  acc[0][0] = MFMA(al0, b0, acc[0][0]);
        acc[0][1] = MFMA(ah0, b1, acc[0][1]);  acc[0][1] = MFMA(al0, b1, acc[0][1]);
        acc[1][0] = MFMA(ah1, b0, acc[1][0]);  acc[1][0] = MFMA(al1, b0, acc[1][0]);
        acc[1][1] = MFMA(ah1, b1, acc[1][1]);  acc[1][1] = MFMA(al1, b1, acc[1][1]);
        if constexpr (SPLITB) {
            v8bf bl0 = *(v8bf*)&Bsl[(wn + lrow) * TKP + quad * 8];
            v8bf bl1 = *(v8bf*)&Bsl[(wn + 16 + lrow) * TKP + quad * 8];
            acc[0][0] = MFMA(ah0, bl0, acc[0][0]);
            acc[0][1] = MFMA(ah0, bl1, acc[0][1]);
            acc[1][0] = MFMA(ah1, bl0, acc[1][0]);
            acc[1][1] = MFMA(ah1, bl1, acc[1][1]);
        }
    }
    #pragma unroll
    for (int i = 0; i < 2; i++)
    #pragma unroll
    for (int j = 0; j < 2; j++) {
        int col = n0 + wn + 16 * j + lrow;
        #pragma unroll
        for (int rg = 0; rg < 4; rg++) {
            int row = m0 + wm + 16 * i + quad * 4 + rg;
            float v = acc[i][j][rg];
            bf16_t h = (bf16_t)v;
            Ch[zo + (size_t)row * HID + col] = h;
            if constexpr (WLO) Cl[zo + (size_t)row * HID + col] = (bf16_t)(v - (float)h);
        }
    }
}

// ---------------- inverse: Qt[b,n,d] = sum_r Gt[n,r] Qfh[b,r,d] -------------
__launch_bounds__(256)
__global__ void inv_kernel(const bf16_t* __restrict__ Gt, const bf16_t* __restrict__ Qf,
                           bf16_t* __restrict__ Qt) {
    __shared__ __align__(16) bf16_t As[64 * TKP];
    __shared__ __align__(16) bf16_t Bs[64 * TKP];
    const bf16_t* Bp = Qf + (size_t)blockIdx.z * NFP * HID;
    int t = threadIdx.x, wave = t >> 6, lane = t & 63;
    int lrow = lane & 15, quad = lane >> 4;
    int m0 = blockIdx.y * 64, n0 = blockIdx.x * 64;
    int wm = (wave >> 1) * 32, wn = (wave & 1) * 32;
    int srow = t >> 2, scol = (t & 3) * 8;
    int brow = t >> 3, bcol = (t & 7) * 8;
    v4f acc[2][2] = {};
    for (int k0 = 0; k0 < NFP; k0 += TBK) {
        __syncthreads();
        *(v8bf*)&As[srow * TKP + scol] = *(const v8bf*)&Gt[(size_t)(m0 + srow) * NFP + k0 + scol];
        {
            v8bf bx = *(const v8bf*)&Bp[(size_t)(k0 + brow) * HID + n0 + bcol];
            #pragma unroll
            for (int e = 0; e < 8; e++) Bs[(bcol + e) * TKP + brow] = bx[e];
        }
        __syncthreads();
        v8bf a0 = *(v8bf*)&As[(wm + lrow) * TKP + quad * 8];
        v8bf a1 = *(v8bf*)&As[(wm + 16 + lrow) * TKP + quad * 8];
        v8bf b0 = *(v8bf*)&Bs[(wn + lrow) * TKP + quad * 8];
        v8bf b1 = *(v8bf*)&Bs[(wn + 16 + lrow) * TKP + quad * 8];
        acc[0][0] = MFMA(a0, b0, acc[0][0]);
        acc[0][1] = MFMA(a0, b1, acc[0][1]);
        acc[1][0] = MFMA(a1, b0, acc[1][0]);
        acc[1][1] = MFMA(a1, b1, acc[1][1]);
    }
    bf16_t* op = Qt + (size_t)blockIdx.z * SEQ * HID;
    #pragma unroll
    for (int i = 0; i < 2; i++)
    #pragma unroll
    for (int j = 0; j < 2; j++) {
        int col = n0 + wn + 16 * j + lrow;
        #pragma unroll
        for (int rg = 0; rg < 4; rg++) {
            int row = m0 + wm + 16 * i + quad * 4 + rg;
            op[(size_t)row * HID + col] = (bf16_t)acc[i][j][rg];
        }
    }
}

// ---------------- flash attention (causal, per-head) ------------------------
__launch_bounds__(256)
__global__ void attn_kernel(const bf16_t* __restrict__ Qt, const bf16_t* __restrict__ Kt,
                            const bf16_t* __restrict__ Vt, bf16_t* __restrict__ TO) {
    __shared__ __align__(16) bf16_t Ks[32 * 72];
    __shared__ __align__(16) bf16_t Vs[64 * 40];
    __shared__ __align__(16) bf16_t Ps[4][16 * 40];
    int t = threadIdx.x, wave = t >> 6, lane = t & 63;
    int lrow = lane & 15, quad = lane >> 4;
    int h = blockIdx.y, b = blockIdx.z;
    int q0 = blockIdx.x * 64;
    const size_t base = ((size_t)b * SEQ) * HID + (size_t)h * HD;

    int qrow = q0 + wave * 16 + lrow;
    v8bf qa0 = *(const v8bf*)&Qt[base + (size_t)qrow * HID + quad * 8];
    v8bf qa1 = *(const v8bf*)&Qt[base + (size_t)qrow * HID + 32 + quad * 8];

    v4f o[4] = {};
    float m_i[4] = {-1e30f, -1e30f, -1e30f, -1e30f};
    float l_i[4] = {0.f, 0.f, 0.f, 0.f};
    int krow = t >> 3, kcol = (t & 7) * 8;
    int nch = (q0 + 64) / 32;
    for (int c = 0; c < nch; c++) {
        int kb = c * 32;
        __syncthreads();
        *(v8bf*)&Ks[krow * 72 + kcol] = *(const v8bf*)&Kt[base + (size_t)(kb + krow) * HID + kcol];
        {
            v8bf vv = *(const v8bf*)&Vt[base + (size_t)(kb + krow) * HID + kcol];
            #pragma unroll
            for (int e = 0; e < 8; e++) Vs[(kcol + e) * 40 + krow] = vv[e];
        }
        __syncthreads();
        v4f s[2] = {};
        #pragma unroll
        for (int ct = 0; ct < 2; ct++) {
            v8bf bk0 = *(v8bf*)&Ks[(ct * 16 + lrow) * 72 + quad * 8];
            v8bf bk1 = *(v8bf*)&Ks[(ct * 16 + lrow) * 72 + 32 + quad * 8];
            s[ct] = MFMA(qa0, bk0, s[ct]);
            s[ct] = MFMA(qa1, bk1, s[ct]);
        }
        float pv0[4], pv1[4];
        #pragma unroll
        for (int r = 0; r < 4; r++) {
            int qg = q0 + wave * 16 + quad * 4 + r;
            float s0 = s[0][r] * 0.125f; if (kb + lrow > qg)      s0 = -1e30f;
            float s1 = s[1][r] * 0.125f; if (kb + 16 + lrow > qg) s1 = -1e30f;
            float mx = fmaxf(s0, s1);
            mx = fmaxf(mx, __shfl_xor(mx, 1));
            mx = fmaxf(mx, __shfl_xor(mx, 2));
            mx = fmaxf(mx, __shfl_xor(mx, 4));
            mx = fmaxf(mx, __shfl_xor(mx, 8));
            float mnew = fmaxf(m_i[r], mx);
            float alpha = __expf(m_i[r] - mnew);
            m_i[r] = mnew;
            float p0 = __expf(s0 - mnew), p1 = __expf(s1 - mnew);
            float rs = p0 + p1;
            rs += __shfl_xor(rs, 1);
            rs += __shfl_xor(rs, 2);
            rs += __shfl_xor(rs, 4);
            rs += __shfl_xor(rs, 8);
            l_i[r] = l_i[r] * alpha + rs;
            o[0][r] *= alpha; o[1][r] *= alpha; o[2][r] *= alpha; o[3][r] *= alpha;
            pv0[r] = p0; pv1[r] = p1;
        }
        #pragma unroll
        for (int r = 0; r < 4; r++) {
            Ps[wave][(quad * 4 + r) * 40 + lrow]      = (bf16_t)pv0[r];
            Ps[wave][(quad * 4 + r) * 40 + 16 + lrow] = (bf16_t)pv1[r];
        }
        __syncthreads();
        v8bf pa = *(v8bf*)&Ps[wave][lrow * 40 + quad * 8];
        #pragma unroll
        for (int dt = 0; dt < 4; dt++) {
            v8bf vb = *(v8bf*)&Vs[(dt * 16 + lrow) * 40 + quad * 8];
            o[dt] = MFMA(pa, vb, o[dt]);
        }
    }
    #pragma unroll
    for (int dt = 0; dt < 4; dt++)
    #pragma unroll
    for (int r = 0; r < 4; r++) {
        int qg = q0 + wave * 16 + quad * 4 + r;
        TO[base + (size_t)qg * HID + dt * 16 + lrow] = (bf16_t)(o[dt][r] / l_i[r]);
    }
}

// ---------------- freq branch: S[f] from split-bf16 Qf,Kf -------------------
__launch_bounds__(256)
__global__ void sfreq_kernel(const bf16_t* __restrict__ Qh, const bf16_t* __restrict__ Ql,
                             const bf16_t* __restrict__ Kh, const bf16_t* __restrict__ Kl,
                             float* __restrict__ Sre, float* __restrict__ Sim) {
    int f = blockIdx.x, b = blockIdx.y, t = threadIdx.x;
    const size_t oc = ((size_t)b * NFP + f) * HID;
    const size_t os = ((size_t)b * NFP + NF + f) * HID;
    float re = 0.f, im = 0.f;
    for (int d = t; d < HID; d += 256) {
        float cq = (float)Qh[oc + d] + (float)Ql[oc + d];
        float sq = (float)Qh[os + d] + (float)Ql[os + d];
        float ck = (float)Kh[oc + d] + (float)Kl[oc + d];
        float sk = (float)Kh[os + d] + (float)Kl[os + d];
        re += cq * ck + sq * sk;   // Re(Qf conj(Kf)), Qf = C - iS
        im += cq * sk - sq * ck;   // Im(Qf conj(Kf))
    }
    #pragma unroll
    for (int msk = 1; msk < 64; msk <<= 1) { re += __shfl_xor(re, msk); im += __shfl_xor(im, msk); }
    __shared__ float rbuf[8];
    int wave = t >> 6, lane = t & 63;
    if (lane == 0) { rbuf[wave] = re; rbuf[4 + wave] = im; }
    __syncthreads();
    if (t == 0) {
        Sre[b * NF + f] = rbuf[0] + rbuf[1] + rbuf[2] + rbuf[3];
        Sim[b * NF + f] = rbuf[4] + rbuf[5] + rbuf[6] + rbuf[7];
    }
}

__launch_bounds__(256)
__global__ void rmean_kernel(const float* __restrict__ Sre, const float* __restrict__ Sim,
                             float* __restrict__ Rm) {
    int b = blockIdx.y;
    int n = blockIdx.x * 256 + threadIdx.x;
    __shared__ float sr[NF], si[NF];
    for (int i = threadIdx.x; i < NF; i += 256) { sr[i] = Sre[b * NF + i]; si[i] = Sim[b * NF + i]; }
    __syncthreads();
    float acc = 0.f;
    for (int r = 0; r < NF; r++) {
        int ph = ((P_LO + r) * n) & (SEQ - 1);
        float ang = (float)(2.0 * DPI / SEQ) * (float)ph;
        float sn, cs;
        sincosf(ang, &sn, &cs);
        acc += sr[r] * cs - si[r] * sn;
    }
    Rm[b * SEQ + n] = acc * (float)(2.0 / ((double)SEQ * (double)HID));
}

__launch_bounds__(256)
__global__ void topk_kernel(const float* __restrict__ Rm, int* __restrict__ Ti,
                            float* __restrict__ Tw) {
    int b = blockIdx.x, t = threadIdx.x;
    __shared__ float vals[SEQ];
    __shared__ float bv[256];
    __shared__ int   bi[256];
    __shared__ float selv[KTOP];
    __shared__ int   seli[KTOP];
    for (int i = t; i < SEQ; i += 256) vals[i] = Rm[b * SEQ + i];
    __syncthreads();
    for (int kk = 0; kk < KTOP; kk++) {
        float best = -INFINITY; int besti = 0;
        for (int i = t; i < SEQ; i += 256) {
            float v = vals[i];
            if (v > best || (v == best && i < besti)) { best = v; besti = i; }
        }
        bv[t] = best; bi[t] = besti;
        __syncthreads();
        for (int s = 128; s > 0; s >>= 1) {
            if (t < s) {
                float v2 = bv[t + s]; int i2 = bi[t + s];
                if (v2 > bv[t] || (v2 == bv[t] && i2 < bi[t])) { bv[t] = v2; bi[t] = i2; }
            }
            __syncthreads();
        }
        if (t == 0) {
            int bb = bi[0]; if ((unsigned)bb >= SEQ) bb = 0;
            selv[kk] = bv[0]; seli[kk] = bb; vals[bb] = -INFINITY;
        }
        __syncthreads();
    }
    if (t == 0) {
        float mx = selv[0];
        for (int i = 1; i < KTOP; i++) mx = fmaxf(mx, selv[i]);
        float s = 0.f, e[KTOP];
        for (int i = 0; i < KTOP; i++) { e[i] = expf(selv[i] - mx); s += e[i]; }
        for (int i = 0; i < KTOP; i++) { Tw[b * KTOP + i] = e[i] / s; Ti[b * KTOP + i] = seli[i]; }
    }
}

// Yc = bf16(0.5*TO + 0.5*sum_k w_k V[(n - tau_k) mod N])
__launch_bounds__(256)
__global__ void combine_kernel(const bf16_t* __restrict__ TO, const bf16_t* __restrict__ V,
                               const int* __restrict__ Ti, const float* __restrict__ Tw,
                               bf16_t* __restrict__ Yc) {
    int b = blockIdx.z, n = blockIdx.y;
    int d = blockIdx.x * 256 + threadIdx.x;
    __shared__ int   ti[KTOP];
    __shared__ float tw[KTOP];
    if (threadIdx.x < KTOP) { ti[threadIdx.x] = Ti[b * KTOP + threadIdx.x]; tw[threadIdx.x] = Tw[b * KTOP + threadIdx.x]; }
    __syncthreads();
    float fo = 0.f;
    #pragma unroll
    for (int kk = 0; kk < KTOP; kk++) {
        int nn = (n - ti[kk] + SEQ) & (SEQ - 1);
        fo += tw[kk] * (float)V[((size_t)b * SEQ + nn) * HID + d];
    }
    size_t off = ((size_t)b * SEQ + n) * HID + d;
    Yc[off] = (bf16_t)(0.5f * (float)TO[off] + 0.5f * fo);
}

// ---------------- launcher ---------------------------------------------------
extern "C" void kernel_launch(void* const* d_in, const int* in_sizes, int n_in,
                              void* d_out, int out_size, void* d_ws, size_t ws_size,
                              hipStream_t stream) {
    (void)in_sizes; (void)n_in; (void)out_size; (void)ws_size;
    const void* X  = d_in[0];
    const void* Wq = d_in[2];
    const void* Wv = d_in[6];
    const void* bv = d_in[7];
    const void* Wk = d_in[4];
    const void* Wo = d_in[8];
    const void* bo = d_in[9];

    // ---- arena: 43.0 MB, tightly scheduled overlays (audited) ----
    const size_t B_TAB = (size_t)NFP * SEQ * 2;          // 2,621,440
    const size_t B_FB  = (size_t)BATCHN * NFP * HID * 2; // 2,621,440
    const size_t B_QKV = (size_t)BATCHN * SEQ * HID * 2; // 8,388,608
    char* w = (char*)d_ws;
    bf16_t* Gt  = (bf16_t*)(w);                          // [0, 2.62M)  live: tabs->inv_V
    bf16_t* Ahi = (bf16_t*)(w + 1 * B_TAB);              // dead after band_fwd
    bf16_t* Alo = (bf16_t*)(w + 2 * B_TAB);
    bf16_t* Xfh = (bf16_t*)(w + 3 * B_TAB);              // dead after proj x3
    bf16_t* Xfl = (bf16_t*)(w + 3 * B_TAB + B_FB);
    bf16_t* Qfh = (bf16_t*)(w + 3 * B_TAB + 2 * B_FB);   // dead after sfreq+inv_Q
    bf16_t* Qfl = (bf16_t*)(w + 3 * B_TAB + 3 * B_FB);   // dead after sfreq
    bf16_t* Kfh = (bf16_t*)(w + 3 * B_TAB + 4 * B_FB);   // dead after sfreq+inv_K
    bf16_t* Kfl = (bf16_t*)(w + 3 * B_TAB + 5 * B_FB);   // dead after sfreq
    bf16_t* Vfh = (bf16_t*)(w + 3 * B_TAB + 6 * B_FB);   // dead after inv_V
    bf16_t* Vm  = (bf16_t*)(w + 3 * B_TAB + 7 * B_FB);   // gemm2 -> combine
    bf16_t* Kt  = (bf16_t*)(w + 3 * B_TAB + 7 * B_FB + B_QKV);  // inv_K -> attn
    char*   sm  =           w + 3 * B_TAB + 7 * B_FB + 2 * B_QKV;
    // overlays (stream-order safe):
    bf16_t* Qt = (bf16_t*)(w + 1 * B_TAB);               // over Ahi..Xfh+part(Xfl); ends 11.01M < Qfh
    bf16_t* Vt = (bf16_t*)(w + 1 * B_TAB + B_QKV);       // [11.01M,19.40M): over Xfl-tail,Qfh,Qfl,Kfh-head
                                                         //   -> must run AFTER sfreq, inv_Q, inv_K
    bf16_t* Yc = Qt;                                     // over Qt (dead after attn)
    bf16_t* TO = (bf16_t*)d_out;                         // d_out[0,8.39M) as scratch (safe both dtypes)
    int*   flag = (int*)sm;
    float* Sre  = (float*)(sm + 256);
    float* Sim  = (float*)(sm + 256 + 4096);
    float* Rm   = (float*)(sm + 256 + 8192);
    int*   Ti   = (int*)  (sm + 256 + 8192 + 16384);
    float* Tw   = (float*)(sm + 256 + 8192 + 16384 + 256);

    // 0. dtype detect (flag: 0 = bf16 inputs, 1 = f32 inputs)
    detect_kernel<<<1, 256, 0, stream>>>((const unsigned short*)X, (const unsigned short*)Wq, flag);
    // 1. tables (dtype-independent)
    tab_band_kernel<<<dim3(SEQ / 256, NFP), 256, 0, stream>>>(Ahi, Alo);
    tab_inv_kernel<<<dim3(NFP / 128, SEQ), 128, 0, stream>>>(Gt);
    // 2. V projection -> Vm (bf16)
    dim3 g1(16, (BATCHN * SEQ) / 64);
    gemm_nt_kernel<bf16_t, bf16_t, bf16_t><<<g1, 256, 0, stream>>>(flag, 0,
        (const bf16_t*)X, (const bf16_t*)Wv, (const bf16_t*)bv, Vm, HID);
    gemm_nt_kernel<float, float, bf16_t><<<g1, 256, 0, stream>>>(flag, 1,
        (const float*)X, (const float*)Wv, (const float*)bv, Vm, HID);
    // 3. band-DFT of X (split output)
    dim3 gF(HID / 64, NFP / 64, BATCHN);
    band_fwd_kernel<bf16_t, false><<<gF, 256, 0, stream>>>(flag, 0, Ahi, Alo, (const bf16_t*)X, Xfh, Xfl);
    band_fwd_kernel<float, true ><<<gF, 256, 0, stream>>>(flag, 1, Ahi, Alo, (const float*)X, Xfh, Xfl);
    // 4. band coeffs of Q,K (split) and V (hi only)
    proj_f_kernel<bf16_t, false, true ><<<gF, 256, 0, stream>>>(flag, 0, Xfh, Xfl, (const bf16_t*)Wq, Qfh, Qfl);
    proj_f_kernel<float,  true,  true ><<<gF, 256, 0, stream>>>(flag, 1, Xfh, Xfl, (const float*)Wq, Qfh, Qfl);
    proj_f_kernel<bf16_t, false, true ><<<gF, 256, 0, stream>>>(flag, 0, Xfh, Xfl, (const bf16_t*)Wk, Kfh, Kfl);
    proj_f_kernel<float,  true,  true ><<<gF, 256, 0, stream>>>(flag, 1, Xfh, Xfl, (const float*)Wk, Kfh, Kfl);
    proj_f_kernel<bf16_t, false, false><<<gF, 256, 0, stream>>>(flag, 0, Xfh, Xfl, (const bf16_t*)Wv, Vfh, nullptr);
    proj_f_kernel<float,  true,  false><<<gF, 256, 0, stream>>>(flag, 1, Xfh, Xfl, (const float*)Wv, Vfh, nullptr);
    // 5. freq-branch stats (must precede Vt overlay writes)
    sfreq_kernel<<<dim3(NF, BATCHN), 256, 0, stream>>>(Qfh, Qfl, Kfh, Kfl, Sre, Sim);
    rmean_kernel<<<dim3(SEQ / 256, BATCHN), 256, 0, stream>>>(Sre, Sim, Rm);
    topk_kernel<<<BATCHN, 256, 0, stream>>>(Rm, Ti, Tw);
    // 6. inverse band transforms (order matters for overlays: Q, K, then V)
    dim3 gI(HID / 64, SEQ / 64, BATCHN);
    inv_kernel<<<gI, 256, 0, stream>>>(Gt, Qfh, Qt);
    inv_kernel<<<gI, 256, 0, stream>>>(Gt, Kfh, Kt);
    inv_kernel<<<gI, 256, 0, stream>>>(Gt, Vfh, Vt);
    // 7. causal flash attention -> TO (in d_out scratch)
    attn_kernel<<<dim3(SEQ / 64, NHEADS, BATCHN), 256, 0, stream>>>(Qt, Kt, Vt, TO);
    // 8. combine -> Yc (ws overlay; avoids d_out read/write race in step 9)
    combine_kernel<<<dim3(HID / 256, SEQ, BATCHN), 256, 0, stream>>>(TO, Vm, Ti, Tw, Yc);
    // 9. output projection (dtype-matched write to d_out)
    gemm_nt_kernel<bf16_t, bf16_t, bf16_t><<<g1, 256, 0, stream>>>(flag, 0,
        Yc, (const bf16_t*)Wo, (const bf16_t*)bo, (bf16_t*)d_out, HID);
    gemm_nt_kernel<bf16_t, float, float><<<g1, 256, 0, stream>>>(flag, 1,
        Yc, (const float*)Wo, (const float*)bo, (float*)d_out, HID);
}

// Round 4
// 571.458 us; speedup vs baseline: 1.3511x; 1.3511x over previous
//
#include <hip/hip_runtime.h>
#include <hip/hip_bf16.h>

// ---------------- problem constants (layer_idx==1 fixed by setup_inputs) ----
#define BATCHN 2
#define SEQ    2048
#define HID    1024
#define NHEADS 16
#define HD     64
#define P_LO   478     // _sample_indices(1) -> p=478, q=785
#define NF     307
#define NF2    614
#define NFP    640     // padded, rows 614..639 zero
#define KTOP   15      // int(2*log(2049))
#define DPI    3.14159265358979323846

typedef __bf16 bf16_t;
typedef bf16_t v8bf __attribute__((ext_vector_type(8)));
typedef float  v4f  __attribute__((ext_vector_type(4)));

#define MFMA(a,b,c) __builtin_amdgcn_mfma_f32_16x16x32_bf16(a,b,c,0,0,0)
// A-frag: m=lane&15, k=(lane>>4)*8+j ; B-frag: n=lane&15, k=(lane>>4)*8+j
// C/D   : col(n)=lane&15, row(m)=(lane>>4)*4+reg

// async global->LDS, 16B per lane; LDS dest must be wave-uniform base + 16*lane
#define GLDS(gp, lp) __builtin_amdgcn_global_load_lds( \
    (const __attribute__((address_space(1))) void*)(gp), \
    (__attribute__((address_space(3))) void*)(lp), 16, 0, 0)

// ---------------- dtype detector: 0 = bf16 inputs, 1 = f32 inputs -----------
__launch_bounds__(256)
__global__ void detect_kernel(const unsigned short* __restrict__ x0,
                              const unsigned short* __restrict__ x1,
                              int* __restrict__ flag) {
    int t = threadIdx.x, bad = 0;
    for (int i = t; i < 8192; i += 256) {
        unsigned e0 = (x0[i] >> 7) & 0xFF; if (e0 >= 0x90) bad++;
        unsigned e1 = (x1[i] >> 7) & 0xFF; if (e1 >= 0x90) bad++;
    }
    __shared__ int s[256];
    s[t] = bad; __syncthreads();
    for (int st = 128; st; st >>= 1) { if (t < st) s[t] += s[t + st]; __syncthreads(); }
    if (t == 0) *flag = (s[0] > 64) ? 1 : 0;
}

// ---------------- tables ----------------------------------------------------
__launch_bounds__(256)
__global__ void tab_band_kernel(bf16_t* __restrict__ Ahi, bf16_t* __restrict__ Alo) {
    int m = blockIdx.x * 256 + threadIdx.x;
    int r = blockIdx.y;
    double v = 0.0;
    if (r < NF2) {
        int f  = P_LO + (r < NF ? r : r - NF);
        int ph = (f * m) & (SEQ - 1);
        double ang = (2.0 * DPI / SEQ) * (double)ph;
        v = (r < NF) ? cos(ang) : sin(ang);
    }
    bf16_t h = (bf16_t)(float)v;
    Ahi[(size_t)r * SEQ + m] = h;
    Alo[(size_t)r * SEQ + m] = (bf16_t)(float)(v - (double)(float)h);
}

__launch_bounds__(128)
__global__ void tab_inv_kernel(bf16_t* __restrict__ Gt) {
    int r = blockIdx.x * 128 + threadIdx.x;
    int n = blockIdx.y;
    float v = 0.f;
    if (r < NF2) {
        int f  = P_LO + (r < NF ? r : r - NF);
        int ph = (f * n) & (SEQ - 1);
        double ang = (2.0 * DPI / SEQ) * (double)ph;
        v = (float)((2.0 / SEQ) * ((r < NF) ? cos(ang) : sin(ang)));
    }
    Gt[(size_t)n * NFP + r] = (bf16_t)v;
}

// ---------------- normalize X: Xh[n][d] + transposed split XTh/XTl[b][d][n] -
__launch_bounds__(256)
__global__ void norm_x_kernel(const int* __restrict__ flag, const void* __restrict__ Xv,
                              bf16_t* __restrict__ Xh, bf16_t* __restrict__ XTh,
                              bf16_t* __restrict__ XTl) {
    int fl = *flag;
    __shared__ float T[64 * 65];
    int t = threadIdx.x;
    int R0 = blockIdx.y * 64, C0 = blockIdx.x * 64;
    int r = t >> 2;
    #pragma unroll
    for (int it = 0; it < 2; it++) {
        int c = (t & 3) * 8 + it * 32;
        float x[8];
        if (fl) {
            const float* p = (const float*)Xv + (size_t)(R0 + r) * HID + C0 + c;
            #pragma unroll
            for (int e = 0; e < 8; e++) x[e] = p[e];
        } else {
            const bf16_t* p = (const bf16_t*)Xv + (size_t)(R0 + r) * HID + C0 + c;
            #pragma unroll
            for (int e = 0; e < 8; e++) x[e] = (float)p[e];
        }
        v8bf h;
        #pragma unroll
        for (int e = 0; e < 8; e++) { h[e] = (bf16_t)x[e]; T[(r) * 65 + c + e] = x[e]; }
        *(v8bf*)&Xh[(size_t)(R0 + r) * HID + C0 + c] = h;
    }
    __syncthreads();
    int b  = blockIdx.y >> 5;          // 2048/64 = 32 row-tiles per batch
    int Rl = R0 - b * SEQ;
    int d  = t >> 2;
    #pragma unroll
    for (int it = 0; it < 2; it++) {
        int n = (t & 3) * 8 + it * 32;
        v8bf h, l;
        #pragma unroll
        for (int e = 0; e < 8; e++) {
            float x = T[(n + e) * 65 + d];
            bf16_t hh = (bf16_t)x;
            h[e] = hh; l[e] = (bf16_t)(x - (float)hh);
        }
        size_t off = ((size_t)b * HID + C0 + d) * SEQ + Rl + n;
        *(v8bf*)&XTh[off] = h;
        *(v8bf*)&XTl[off] = l;
    }
}

// ---------------- dense NT GEMM + bias: C[M,1024] = A @ Braw^T --------------
// A bf16 (global_load_lds); B raw weights (dtype branch); outmode 0: bf16 out,
// 1: flag-based (f32 when fl).
__launch_bounds__(256)
__global__ void gemm_nt_b(const int* __restrict__ flag, const bf16_t* __restrict__ A,
                          const void* __restrict__ Braw, const void* __restrict__ biasraw,
                          void* __restrict__ Out, int outmode) {
    int fl = *flag;
    __shared__ __align__(16) bf16_t As[64 * 32];
    __shared__ __align__(16) bf16_t Bs[64 * 32];
    int t = threadIdx.x, wave = t >> 6, lane = t & 63;
    int lrow = lane & 15, quad = lane >> 4;
    int m0 = blockIdx.y * 64, n0 = blockIdx.x * 64;
    int wm = (wave >> 1) * 32, wn = (wave & 1) * 32;
    int srow = t >> 2, scol = (t & 3) * 8;
    v4f acc[2][2] = {};
    for (int k0 = 0; k0 < HID; k0 += 32) {
        __syncthreads();
        GLDS(&A[(size_t)(m0 + srow) * HID + k0 + scol], &As[srow * 32 + scol]);
        {
            float xb[8];
            if (fl) {
                const float* p = (const float*)Braw + (size_t)(n0 + srow) * HID + k0 + scol;
                #pragma unroll
                for (int e = 0; e < 8; e++) xb[e] = p[e];
            } else {
                const bf16_t* p = (const bf16_t*)Braw + (size_t)(n0 + srow) * HID + k0 + scol;
                #pragma unroll
                for (int e = 0; e < 8; e++) xb[e] = (float)p[e];
            }
            v8bf h;
            #pragma unroll
            for (int e = 0; e < 8; e++) h[e] = (bf16_t)xb[e];
            *(v8bf*)&Bs[srow * 32 + scol] = h;
        }
        __syncthreads();
        v8bf a0 = *(v8bf*)&As[(wm + lrow) * 32 + quad * 8];
        v8bf a1 = *(v8bf*)&As[(wm + 16 + lrow) * 32 + quad * 8];
        v8bf b0 = *(v8bf*)&Bs[(wn + lrow) * 32 + quad * 8];
        v8bf b1 = *(v8bf*)&Bs[(wn + 16 + lrow) * 32 + quad * 8];
        acc[0][0] = MFMA(a0, b0, acc[0][0]);
        acc[0][1] = MFMA(a0, b1, acc[0][1]);
        acc[1][0] = MFMA(a1, b0, acc[1][0]);
        acc[1][1] = MFMA(a1, b1, acc[1][1]);
    }
    #pragma unroll
    for (int i = 0; i < 2; i++)
    #pragma unroll
    for (int j = 0; j < 2; j++) {
        int col = n0 + wn + 16 * j + lrow;
        float bvv = fl ? ((const float*)biasraw)[col] : (float)((const bf16_t*)biasraw)[col];
        #pragma unroll
        for (int rg = 0; rg < 4; rg++) {
            int row = m0 + wm + 16 * i + quad * 4 + rg;
            float v = acc[i][j][rg] + bvv;
            size_t off = (size_t)row * HID + col;
            if (outmode == 1 && fl) ((float*)Out)[off] = v;
            else ((bf16_t*)Out)[off] = (bf16_t)v;
        }
    }
}

// ---------------- band forward: Xf[b][r][d] = sum_m A[r][m] X[b][m][d] ------
// NT on (Ahi/Alo)[r][m] x (XTh/XTl)[b][d][m], 3-pass. Output split hi/lo.
__launch_bounds__(256)
__global__ void band_fwd(const bf16_t* __restrict__ Ahi, const bf16_t* __restrict__ Alo,
                         const bf16_t* __restrict__ XTh, const bf16_t* __restrict__ XTl,
                         bf16_t* __restrict__ Xfh, bf16_t* __restrict__ Xfl) {
    __shared__ __align__(16) bf16_t Ah[64 * 32], Al[64 * 32], Bh[64 * 32], Bl[64 * 32];
    int t = threadIdx.x, wave = t >> 6, lane = t & 63;
    int lrow = lane & 15, quad = lane >> 4;
    int m0 = blockIdx.y * 64, n0 = blockIdx.x * 64, b = blockIdx.z;
    int wm = (wave >> 1) * 32, wn = (wave & 1) * 32;
    int srow = t >> 2, scol = (t & 3) * 8;
    const bf16_t* bth = XTh + (size_t)b * HID * SEQ;
    const bf16_t* btl = XTl + (size_t)b * HID * SEQ;
    v4f acc[2][2] = {};
    for (int k0 = 0; k0 < SEQ; k0 += 32) {
        __syncthreads();
        GLDS(&Ahi[(size_t)(m0 + srow) * SEQ + k0 + scol], &Ah[srow * 32 + scol]);
        GLDS(&Alo[(size_t)(m0 + srow) * SEQ + k0 + scol], &Al[srow * 32 + scol]);
        GLDS(&bth[(size_t)(n0 + srow) * SEQ + k0 + scol], &Bh[srow * 32 + scol]);
        GLDS(&btl[(size_t)(n0 + srow) * SEQ + k0 + scol], &Bl[srow * 32 + scol]);
        __syncthreads();
        v8bf ah0 = *(v8bf*)&Ah[(wm + lrow) * 32 + quad * 8];
        v8bf ah1 = *(v8bf*)&Ah[(wm + 16 + lrow) * 32 + quad * 8];
        v8bf al0 = *(v8bf*)&Al[(wm + lrow) * 32 + quad * 8];
        v8bf al1 = *(v8bf*)&Al[(wm + 16 + lrow) * 32 + quad * 8];
        v8bf bh0 = *(v8bf*)&Bh[(wn + lrow) * 32 + quad * 8];
        v8bf bh1 = *(v8bf*)&Bh[(wn + 16 + lrow) * 32 + quad * 8];
        v8bf bl0 = *(v8bf*)&Bl[(wn + lrow) * 32 + quad * 8];
        v8bf bl1 = *(v8bf*)&Bl[(wn + 16 + lrow) * 32 + quad * 8];
        acc[0][0] = MFMA(ah0, bh0, acc[0][0]); acc[0][0] = MFMA(ah0, bl0, acc[0][0]); acc[0][0] = MFMA(al0, bh0, acc[0][0]);
        acc[0][1] = MFMA(ah0, bh1, acc[0][1]); acc[0][1] = MFMA(ah0, bl1, acc[0][1]); acc[0][1] = MFMA(al0, bh1, acc[0][1]);
        acc[1][0] = MFMA(ah1, bh0, acc[1][0]); acc[1][0] = MFMA(ah1, bl0, acc[1][0]); acc[1][0] = MFMA(al1, bh0, acc[1][0]);
        acc[1][1] = MFMA(ah1, bh1, acc[1][1]); acc[1][1] = MFMA(ah1, bl1, acc[1][1]); acc[1][1] = MFMA(al1, bh1, acc[1][1]);
    }
    bf16_t* oh = Xfh + (size_t)b * NFP * HID;
    bf16_t* ol = Xfl + (size_t)b * NFP * HID;
    #pragma unroll
    for (int i = 0; i < 2; i++)
    #pragma unroll
    for (int j = 0; j < 2; j++) {
        int col = n0 + wn + 16 * j + lrow;
        #pragma unroll
        for (int rg = 0; rg < 4; rg++) {
            int row = m0 + wm + 16 * i + quad * 4 + rg;
            float v = acc[i][j][rg];
            bf16_t h = (bf16_t)v;
            oh[(size_t)row * HID + col] = h;
            ol[(size_t)row * HID + col] = (bf16_t)(v - (float)h);
        }
    }
}

// ---------------- proj: Qf[b][r][j] = sum_e Xf[b][r][e] W[j][e] -------------
// QK: 3-pass (W split), writes Ch+Cl+CT. else 2-pass, writes CT only.
template<bool QK>
__launch_bounds__(256)
__global__ void proj_f(const int* __restrict__ flag, const bf16_t* __restrict__ Xfh,
                       const bf16_t* __restrict__ Xfl, const void* __restrict__ Wraw,
                       bf16_t* __restrict__ Ch, bf16_t* __restrict__ Cl,
                       bf16_t* __restrict__ CT) {
    int fl = *flag;
    __shared__ __align__(16) bf16_t Ah[64 * 32], Al[64 * 32], Bh[64 * 32];
    __shared__ __align__(16) bf16_t Bl[QK ? 64 * 32 : 8];
    int t = threadIdx.x, wave = t >> 6, lane = t & 63;
    int lrow = lane & 15, quad = lane >> 4;
    int m0 = blockIdx.y * 64, n0 = blockIdx.x * 64;
    int wm = (wave >> 1) * 32, wn = (wave & 1) * 32;
    int srow = t >> 2, scol = (t & 3) * 8;
    const size_t zo = (size_t)blockIdx.z * NFP * HID;
    v4f acc[2][2] = {};
    for (int k0 = 0; k0 < HID; k0 += 32) {
        __syncthreads();
        GLDS(&Xfh[zo + (size_t)(m0 + srow) * HID + k0 + scol], &Ah[srow * 32 + scol]);
        GLDS(&Xfl[zo + (size_t)(m0 + srow) * HID + k0 + scol], &Al[srow * 32 + scol]);
        {
            float xb[8];
            if (fl) {
                const float* p = (const float*)Wraw + (size_t)(n0 + srow) * HID + k0 + scol;
                #pragma unroll
                for (int e = 0; e < 8; e++) xb[e] = p[e];
            } else {
                const bf16_t* p = (const bf16_t*)Wraw + (size_t)(n0 + srow) * HID + k0 + scol;
                #pragma unroll
                for (int e = 0; e < 8; e++) xb[e] = (float)p[e];
            }
            v8bf h, l;
            #pragma unroll
            for (int e = 0; e < 8; e++) {
                bf16_t hh = (bf16_t)xb[e];
                h[e] = hh; l[e] = (bf16_t)(xb[e] - (float)hh);
            }
            *(v8bf*)&Bh[srow * 32 + scol] = h;
            if constexpr (QK) *(v8bf*)&Bl[srow * 32 + scol] = l;
        }
        __syncthreads();
        v8bf ah0 = *(v8bf*)&Ah[(wm + lrow) * 32 + quad * 8];
        v8bf ah1 = *(v8bf*)&Ah[(wm + 16 + lrow) * 32 + quad * 8];
        v8bf al0 = *(v8bf*)&Al[(wm + lrow) * 32 + quad * 8];
        v8bf al1 = *(v8bf*)&Al[(wm + 16 + lrow) * 32 + quad * 8];
        v8bf bh0 = *(v8bf*)&Bh[(wn + lrow) * 32 + quad * 8];
        v8bf bh1 = *(v8bf*)&Bh[(wn + 16 + lrow) * 32 + quad * 8];
        acc[0][0] = MFMA(ah0, bh0, acc[0][0]); acc[0][0] = MFMA(al0, bh0, acc[0][0]);
        acc[0][1] = MFMA(ah0, bh1, acc[0][1]); acc[0][1] = MFMA(al0, bh1, acc[0][1]);
        acc[1][0] = MFMA(ah1, bh0, acc[1][0]); acc[1][0] = MFMA(al1, bh0, acc[1][0]);
        acc[1][1] = MFMA(ah1, bh1, acc[1][1]); acc[1][1] = MFMA(al1, bh1, acc[1][1]);
        if constexpr (QK) {
            v8bf bl0 = *(v8bf*)&Bl[(wn + lrow) * 32 + quad * 8];
            v8bf bl1 = *(v8bf*)&Bl[(wn + 16 + lrow) * 32 + quad * 8];
            acc[0][0] = MFMA(ah0, bl0, acc[0][0]);
            acc[0][1] = MFMA(ah0, bl1, acc[0][1]);
            acc[1][0] = MFMA(ah1, bl0, acc[1][0]);
            acc[1][1] = MFMA(ah1, bl1, acc[1][1]);
        }
    }
    #pragma unroll
    for (int i = 0; i < 2; i++)
    #pragma unroll
    for (int j = 0; j < 2; j++) {
        int col = n0 + wn + 16 * j + lrow;
        #pragma unroll
        for (int rg = 0; rg < 4; rg++) {
            int row = m0 + wm + 16 * i + quad * 4 + rg;
            float v = acc[i][j][rg];
            bf16_t h = (bf16_t)v;
            if constexpr (QK) {
                Ch[zo + (size_t)row * HID + col] = h;
                Cl[zo + (size_t)row * HID + col] = (bf16_t)(v - (float)h);
            }
            CT[zo + (size_t)col * NFP + row] = h;
        }
    }
}

// ---------------- inverse: C[b][n][d] = sum_r Gt[n][r] QfT[b][d][r] ---------
template<bool TRANS>   // TRANS: write Out[b][d][n] (for V^T), else Out[b][n][d]
__launch_bounds__(256)
__global__ void inv_f(const bf16_t* __restrict__ Gt, const bf16_t* __restrict__ BT,
                      bf16_t* __restrict__ Out) {
    __shared__ __align__(16) bf16_t As[64 * 32], Bs[64 * 32];
    int t = threadIdx.x, wave = t >> 6, lane = t & 63;
    int lrow = lane & 15, quad = lane >> 4;
    int m0 = blockIdx.y * 64, n0 = blockIdx.x * 64, b = blockIdx.z;
    int wm = (wave >> 1) * 32, wn = (wave & 1) * 32;
    int srow = t >> 2, scol = (t & 3) * 8;
    const bf16_t* Bp = BT + (size_t)b * HID * NFP;
    v4f acc[2][2] = {};
    for (int k0 = 0; k0 < NFP; k0 += 32) {
        __syncthreads();
        GLDS(&Gt[(size_t)(m0 + srow) * NFP + k0 + scol], &As[srow * 32 + scol]);
        GLDS(&Bp[(size_t)(n0 + srow) * NFP + k0 + scol], &Bs[srow * 32 + scol]);
        __syncthreads();
        v8bf a0 = *(v8bf*)&As[(wm + lrow) * 32 + quad * 8];
        v8bf a1 = *(v8bf*)&As[(wm + 16 + lrow) * 32 + quad * 8];
        v8bf b0 = *(v8bf*)&Bs[(wn + lrow) * 32 + quad * 8];
        v8bf b1 = *(v8bf*)&Bs[(wn + 16 + lrow) * 32 + quad * 8];
        acc[0][0] = MFMA(a0, b0, acc[0][0]);
        acc[0][1] = MFMA(a0, b1, acc[0][1]);
        acc[1][0] = MFMA(a1, b0, acc[1][0]);
        acc[1][1] = MFMA(a1, b1, acc[1][1]);
    }
    #pragma unroll
    for (int i = 0; i < 2; i++)
    #pragma unroll
    for (int j = 0; j < 2; j++) {
        int col = n0 + wn + 16 * j + lrow;
        #pragma unroll
        for (int rg = 0; rg < 4; rg++) {
            int row = m0 + wm + 16 * i + quad * 4 + rg;
            bf16_t v = (bf16_t)acc[i][j][rg];
            if constexpr (TRANS) Out[((size_t)b * HID + col) * SEQ + row] = v;
            else                 Out[(size_t)b * SEQ * HID + (size_t)row * HID + col] = v;
        }
    }
}

// ---------------- flash attention: 64-q tile, 64-key chunks, V^T input ------
__launch_bounds__(256)
__global__ void attn_kernel(const bf16_t* __restrict__ Qt, const bf16_t* __restrict__ Kt,
                            const bf16_t* __restrict__ VT, bf16_t* __restrict__ TO) {
    __shared__ __align__(16) bf16_t Ks[64 * 72];
    __shared__ __align__(16) bf16_t Vs[64 * 72];
    __shared__ __align__(16) bf16_t Ps[4 * 16 * 72];
    int t = threadIdx.x, wave = t >> 6, lane = t & 63;
    int lrow = lane & 15, quad = lane >> 4;
    int h = blockIdx.y, b = blockIdx.z;
    int q0 = (gridDim.x - 1 - blockIdx.x) * 64;    // heavy tiles dispatch first
    const size_t base = (size_t)b * SEQ * HID + (size_t)h * HD;
    const bf16_t* vb_ = VT + ((size_t)b * HID + h * HD) * SEQ;
    bf16_t* Pw = &Ps[wave * 16 * 72];

    int qrow = q0 + wave * 16 + lrow;
    v8bf qa0 = *(const v8bf*)&Qt[base + (size_t)qrow * HID + quad * 8];
    v8bf qa1 = *(const v8bf*)&Qt[base + (size_t)qrow * HID + 32 + quad * 8];

    v4f o[4] = {};
    float m_i[4] = {-1e30f, -1e30f, -1e30f, -1e30f};
    float l_i[4] = {0.f, 0.f, 0.f, 0.f};
    int srow = t >> 2;
    int nch = q0 / 64 + 1;
    for (int c = 0; c < nch; c++) {
        int kb = c * 64;
        bool masked = (kb == q0);
        __syncthreads();
        #pragma unroll
        for (int rep = 0; rep < 2; rep++) {
            int cc = (t & 3) * 8 + rep * 32;
            *(v8bf*)&Ks[srow * 72 + cc] = *(const v8bf*)&Kt[base + (size_t)(kb + srow) * HID + cc];
            *(v8bf*)&Vs[srow * 72 + cc] = *(const v8bf*)&vb_[(size_t)srow * SEQ + kb + cc];
        }
        __syncthreads();
        v4f s[4] = {};
        #pragma unroll
        for (int ct = 0; ct < 4; ct++) {
            v8bf k0f = *(v8bf*)&Ks[(ct * 16 + lrow) * 72 + quad * 8];
            v8bf k1f = *(v8bf*)&Ks[(ct * 16 + lrow) * 72 + 32 + quad * 8];
            s[ct] = MFMA(qa0, k0f, s[ct]);
            s[ct] = MFMA(qa1, k1f, s[ct]);
        }
        #pragma unroll
        for (int r = 0; r < 4; r++) {
            int qg = q0 + wave * 16 + quad * 4 + r;
            float sv[4];
            #pragma unroll
            for (int ct = 0; ct < 4; ct++) {
                sv[ct] = s[ct][r] * 0.125f;
                if (masked && (kb + ct * 16 + lrow > qg)) sv[ct] = -1e30f;
            }
            float mx = fmaxf(fmaxf(sv[0], sv[1]), fmaxf(sv[2], sv[3]));
            mx = fmaxf(mx, __shfl_xor(mx, 1));
            mx = fmaxf(mx, __shfl_xor(mx, 2));
            mx = fmaxf(mx, __shfl_xor(mx, 4));
            mx = fmaxf(mx, __shfl_xor(mx, 8));
            float mnew = fmaxf(m_i[r], mx);
            float alpha = __expf(m_i[r] - mnew);
            m_i[r] = mnew;
            float rs = 0.f;
            #pragma unroll
            for (int ct = 0; ct < 4; ct++) { sv[ct] = __expf(sv[ct] - mnew); rs += sv[ct]; }
            rs += __shfl_xor(rs, 1);
            rs += __shfl_xor(rs, 2);
            rs += __shfl_xor(rs, 4);
            rs += __shfl_xor(rs, 8);
            l_i[r] = l_i[r] * alpha + rs;
            o[0][r] *= alpha; o[1][r] *= alpha; o[2][r] *= alpha; o[3][r] *= alpha;
            #pragma unroll
            for (int ct = 0; ct < 4; ct++)
                Pw[(quad * 4 + r) * 72 + ct * 16 + lrow] = (bf16_t)sv[ct];
        }
        __syncthreads();   // also re-protects Ks/Vs; Ps intra-wave safe anyway
        v8bf pa0 = *(v8bf*)&Pw[lrow * 72 + quad * 8];
        v8bf pa1 = *(v8bf*)&Pw[lrow * 72 + 32 + quad * 8];
        #pragma unroll
        for (int dt = 0; dt < 4; dt++) {
            v8bf vb0 = *(v8bf*)&Vs[(dt * 16 + lrow) * 72 + quad * 8];
            v8bf vb1 = *(v8bf*)&Vs[(dt * 16 + lrow) * 72 + 32 + quad * 8];
            o[dt] = MFMA(pa0, vb0, o[dt]);
            o[dt] = MFMA(pa1, vb1, o[dt]);
        }
    }
    #pragma unroll
    for (int dt = 0; dt < 4; dt++)
    #pragma unroll
    for (int r = 0; r < 4; r++) {
        int qg = q0 + wave * 16 + quad * 4 + r;
        TO[base + (size_t)qg * HID + dt * 16 + lrow] = (bf16_t)(o[dt][r] / l_i[r]);
    }
}

// ---------------- freq branch ------------------------------------------------
__launch_bounds__(256)
__global__ void sfreq_kernel(const bf16_t* __restrict__ Qh, const bf16_t* __restrict__ Ql,
                             const bf16_t* __restrict__ Kh, const bf16_t* __restrict__ Kl,
                             float* __restrict__ Sre, float* __restrict__ Sim) {
    int f = blockIdx.x, b = blockIdx.y, t = threadIdx.x;
    const size_t oc = ((size_t)b * NFP + f) * HID;
    const size_t os = ((size_t)b * NFP + NF + f) * HID;
    float re = 0.f, im = 0.f;
    for (int d = t; d < HID; d += 256) {
        float cq = (float)Qh[oc + d] + (float)Ql[oc + d];
        float sq = (float)Qh[os + d] + (float)Ql[os + d];
        float ck = (float)Kh[oc + d] + (float)Kl[oc + d];
        float sk = (float)Kh[os + d] + (float)Kl[os + d];
        re += cq * ck + sq * sk;
        im += cq * sk - sq * ck;
    }
    #pragma unroll
    for (int msk = 1; msk < 64; msk <<= 1) { re += __shfl_xor(re, msk); im += __shfl_xor(im, msk); }
    __shared__ float rbuf[8];
    int wave = t >> 6, lane = t & 63;
    if (lane == 0) { rbuf[wave] = re; rbuf[4 + wave] = im; }
    __syncthreads();
    if (t == 0) {
        Sre[b * NF + f] = rbuf[0] + rbuf[1] + rbuf[2] + rbuf[3];
        Sim[b * NF + f] = rbuf[4] + rbuf[5] + rbuf[6] + rbuf[7];
    }
}

__launch_bounds__(256)
__global__ void rmean_kernel(const float* __restrict__ Sre, const float* __restrict__ Sim,
                             float* __restrict__ Rm) {
    int b = blockIdx.y;
    int n = blockIdx.x * 256 + threadIdx.x;
    __shared__ float sr[NF], si[NF];
    for (int i = threadIdx.x; i < NF; i += 256) { sr[i] = Sre[b * NF + i]; si[i] = Sim[b * NF + i]; }
    __syncthreads();
    float acc = 0.f;
    for (int r = 0; r < NF; r++) {
        int ph = ((P_LO + r) * n) & (SEQ - 1);
        float ang = (float)(2.0 * DPI / SEQ) * (float)ph;
        float sn, cs;
        sincosf(ang, &sn, &cs);
        acc += sr[r] * cs - si[r] * sn;
    }
    Rm[b * SEQ + n] = acc * (float)(2.0 / ((double)SEQ * (double)HID));
}

__launch_bounds__(256)
__global__ void topk_kernel(const float* __restrict__ Rm, int* __restrict__ Ti,
                            float* __restrict__ Tw) {
    int b = blockIdx.x, t = threadIdx.x;
    __shared__ float vals[SEQ];
    __shared__ float bv[256];
    __shared__ int   bi[256];
    __shared__ float selv[KTOP];
    __shared__ int   seli[KTOP];
    for (int i = t; i < SEQ; i += 256) vals[i] = Rm[b * SEQ + i];
    __syncthreads();
    for (int kk = 0; kk < KTOP; kk++) {
        float best = -INFINITY; int besti = 0;
        for (int i = t; i < SEQ; i += 256) {
            float v = vals[i];
            if (v > best || (v == best && i < besti)) { best = v; besti = i; }
        }
        bv[t] = best; bi[t] = besti;
        __syncthreads();
        for (int s = 128; s > 0; s >>= 1) {
            if (t < s) {
                float v2 = bv[t + s]; int i2 = bi[t + s];
                if (v2 > bv[t] || (v2 == bv[t] && i2 < bi[t])) { bv[t] = v2; bi[t] = i2; }
            }
            __syncthreads();
        }
        if (t == 0) {
            int bb = bi[0]; if ((unsigned)bb >= SEQ) bb = 0;
            selv[kk] = bv[0]; seli[kk] = bb; vals[bb] = -INFINITY;
        }
        __syncthreads();
    }
    if (t == 0) {
        float mx = selv[0];
        for (int i = 1; i < KTOP; i++) mx = fmaxf(mx, selv[i]);
        float s = 0.f, e[KTOP];
        for (int i = 0; i < KTOP; i++) { e[i] = expf(selv[i] - mx); s += e[i]; }
        for (int i = 0; i < KTOP; i++) { Tw[b * KTOP + i] = e[i] / s; Ti[b * KTOP + i] = seli[i]; }
    }
}

__launch_bounds__(256)
__global__ void combine_kernel(const bf16_t* __restrict__ TO, const bf16_t* __restrict__ V,
                               const int* __restrict__ Ti, const float* __restrict__ Tw,
                               bf16_t* __restrict__ Yc) {
    int b = blockIdx.z, n = blockIdx.y;
    int d = blockIdx.x * 256 + threadIdx.x;
    __shared__ int   ti[KTOP];
    __shared__ float tw[KTOP];
    if (threadIdx.x < KTOP) { ti[threadIdx.x] = Ti[b * KTOP + threadIdx.x]; tw[threadIdx.x] = Tw[b * KTOP + threadIdx.x]; }
    __syncthreads();
    float fo = 0.f;
    #pragma unroll
    for (int kk = 0; kk < KTOP; kk++) {
        int nn = (n - ti[kk] + SEQ) & (SEQ - 1);
        fo += tw[kk] * (float)V[((size_t)b * SEQ + nn) * HID + d];
    }
    size_t off = ((size_t)b * SEQ + n) * HID + d;
    Yc[off] = (bf16_t)(0.5f * (float)TO[off] + 0.5f * fo);
}

// ---------------- launcher ---------------------------------------------------
extern "C" void kernel_launch(void* const* d_in, const int* in_sizes, int n_in,
                              void* d_out, int out_size, void* d_ws, size_t ws_size,
                              hipStream_t stream) {
    (void)in_sizes; (void)n_in; (void)out_size; (void)ws_size;
    const void* X  = d_in[0];
    const void* Wq = d_in[2];
    const void* Wk = d_in[4];
    const void* Wv = d_in[6];
    const void* bv = d_in[7];
    const void* Wo = d_in[8];
    const void* bo = d_in[9];

    // ---- arena 41.5 MB, stream-ordered overlays (audited) ----
    const size_t SZ_X   = (size_t)BATCHN * SEQ * HID * 2;   // 8,388,608
    const size_t SZ_TAB = (size_t)NFP * SEQ * 2;            // 2,621,440
    const size_t SZ_F   = (size_t)BATCHN * NFP * HID * 2;   // 2,621,440
    char* w = (char*)d_ws;
    // P0 [0, 8.4M): Xh -> {Xfh@0, Xfl@2.62M} -> Qt -> Yc
    bf16_t* Xh  = (bf16_t*)(w);
    bf16_t* Xfh = (bf16_t*)(w);
    bf16_t* Xfl = (bf16_t*)(w + SZ_F);
    bf16_t* Qt  = (bf16_t*)(w);
    bf16_t* Yc  = (bf16_t*)(w);
    // P1 [8.4M, 16.8M): XTh -> {Qfh, Qfl, Kfh} -> Kt
    bf16_t* XTh = (bf16_t*)(w + SZ_X);
    bf16_t* Qfh = (bf16_t*)(w + SZ_X);
    bf16_t* Qfl = (bf16_t*)(w + SZ_X + SZ_F);
    bf16_t* Kfh = (bf16_t*)(w + SZ_X + 2 * SZ_F);
    bf16_t* Kt  = (bf16_t*)(w + SZ_X);
    // P2 [16.8M, 25.2M): XTl -> {Kfl, QfT, KfT} -> VT
    bf16_t* XTl = (bf16_t*)(w + 2 * SZ_X);
    bf16_t* Kfl = (bf16_t*)(w + 2 * SZ_X);
    bf16_t* QfT = (bf16_t*)(w + 2 * SZ_X + SZ_F);
    bf16_t* KfT = (bf16_t*)(w + 2 * SZ_X + 2 * SZ_F);
    bf16_t* VT  = (bf16_t*)(w + 2 * SZ_X);
    // P3 [25.2M, 33.6M): Vm
    bf16_t* Vm  = (bf16_t*)(w + 3 * SZ_X);
    // P4 [33.6M, 36.2M): Gt
    bf16_t* Gt  = (bf16_t*)(w + 4 * SZ_X);
    // P5 [36.2M, 41.4M): {Ahi, Alo} -> VfT (over Ahi slot)
    bf16_t* Ahi = (bf16_t*)(w + 4 * SZ_X + SZ_TAB);
    bf16_t* Alo = (bf16_t*)(w + 4 * SZ_X + 2 * SZ_TAB);
    bf16_t* VfT = (bf16_t*)(w + 4 * SZ_X + SZ_TAB);
    // P6 smalls
    char*  sm  = w + 4 * SZ_X + 3 * SZ_TAB;
    int*   flag = (int*)sm;
    float* Sre  = (float*)(sm + 256);
    float* Sim  = (float*)(sm + 256 + 4096);
    float* Rm   = (float*)(sm + 256 + 8192);
    int*   Ti   = (int*)  (sm + 256 + 8192 + 16384);
    float* Tw   = (float*)(sm + 256 + 8192 + 16384 + 256);
    bf16_t* TO  = (bf16_t*)d_out;   // d_out scratch (>= 8.39MB both dtypes)

    detect_kernel<<<1, 256, 0, stream>>>((const unsigned short*)X, (const unsigned short*)Wq, flag);
    norm_x_kernel<<<dim3(16, 64), 256, 0, stream>>>(flag, X, Xh, XTh, XTl);
    tab_band_kernel<<<dim3(SEQ / 256, NFP), 256, 0, stream>>>(Ahi, Alo);
    tab_inv_kernel<<<dim3(NFP / 128, SEQ), 128, 0, stream>>>(Gt);
    // V = X @ Wv^T + bv
    gemm_nt_b<<<dim3(16, 64), 256, 0, stream>>>(flag, Xh, Wv, bv, Vm, 0);
    // band DFT of X (3-pass split)
    band_fwd<<<dim3(16, NFP / 64, BATCHN), 256, 0, stream>>>(Ahi, Alo, XTh, XTl, Xfh, Xfl);
    // band coeffs: Q,K split (+transposed hi), V transposed hi only
    dim3 gP(16, NFP / 64, BATCHN);
    proj_f<true ><<<gP, 256, 0, stream>>>(flag, Xfh, Xfl, Wq, Qfh, Qfl, QfT);
    proj_f<true ><<<gP, 256, 0, stream>>>(flag, Xfh, Xfl, Wk, Kfh, Kfl, KfT);
    proj_f<false><<<gP, 256, 0, stream>>>(flag, Xfh, Xfl, Wv, nullptr, nullptr, VfT);
    // freq-branch stats (before overlays of Qfh/Qfl/Kfh/Kfl)
    sfreq_kernel<<<dim3(NF, BATCHN), 256, 0, stream>>>(Qfh, Qfl, Kfh, Kfl, Sre, Sim);
    rmean_kernel<<<dim3(SEQ / 256, BATCHN), 256, 0, stream>>>(Sre, Sim, Rm);
    topk_kernel<<<BATCHN, 256, 0, stream>>>(Rm, Ti, Tw);
    // inverse band transforms (order: Q, K, then V — overlay safety)
    dim3 gI(16, SEQ / 64, BATCHN);
    inv_f<false><<<gI, 256, 0, stream>>>(Gt, QfT, Qt);
    inv_f<false><<<gI, 256, 0, stream>>>(Gt, KfT, Kt);
    inv_f<true ><<<gI, 256, 0, stream>>>(Gt, VfT, VT);
    // attention -> TO (d_out scratch)
    attn_kernel<<<dim3(SEQ / 64, NHEADS, BATCHN), 256, 0, stream>>>(Qt, Kt, VT, TO);
    // combine -> Yc
    combine_kernel<<<dim3(HID / 256, SEQ, BATCHN), 256, 0, stream>>>(TO, Vm, Ti, Tw, Yc);
    // output projection (flag-based output dtype)
    gemm_nt_b<<<dim3(16, 64), 256, 0, stream>>>(flag, Yc, Wo, bo, d_out, 1);
}

// Round 5
// 548.672 us; speedup vs baseline: 1.4072x; 1.0415x over previous
//
#include <hip/hip_runtime.h>
#include <hip/hip_bf16.h>

// ---------------- problem constants (layer_idx==1 fixed by setup_inputs) ----
#define BATCHN 2
#define SEQ    2048
#define HID    1024
#define NHEADS 16
#define HD     64
#define P_LO   478     // _sample_indices(1) -> p=478, q=785
#define NF     307
#define NF2    614
#define NFP    640     // padded, rows 614..639 zero
#define KTOP   15      // int(2*log(2049))
#define DPI    3.14159265358979323846

typedef __bf16 bf16_t;
typedef bf16_t v8bf __attribute__((ext_vector_type(8)));
typedef bf16_t v4bf __attribute__((ext_vector_type(4)));
typedef float  v4f  __attribute__((ext_vector_type(4)));

#define MFMA(a,b,c) __builtin_amdgcn_mfma_f32_16x16x32_bf16(a,b,c,0,0,0)
// A-frag: m=lane&15, k=(lane>>4)*8+j ; B-frag: n=lane&15, k=(lane>>4)*8+j
// C/D   : col(n)=lane&15, row(m)=(lane>>4)*4+reg

// async global->LDS, 16B per lane; LDS dest = wave-uniform base + 16*lane
#define GLDS(gp, lp) __builtin_amdgcn_global_load_lds( \
    (const __attribute__((address_space(1))) void*)(gp), \
    (__attribute__((address_space(3))) void*)(lp), 16, 0, 0)

// ---------------- dtype detector: 0 = bf16 inputs, 1 = f32 inputs -----------
__launch_bounds__(256)
__global__ void detect_kernel(const unsigned short* __restrict__ x0,
                              const unsigned short* __restrict__ x1,
                              int* __restrict__ flag) {
    int t = threadIdx.x, bad = 0;
    for (int i = t; i < 8192; i += 256) {
        unsigned e0 = (x0[i] >> 7) & 0xFF; if (e0 >= 0x90) bad++;
        unsigned e1 = (x1[i] >> 7) & 0xFF; if (e1 >= 0x90) bad++;
    }
    __shared__ int s[256];
    s[t] = bad; __syncthreads();
    for (int st = 128; st; st >>= 1) { if (t < st) s[t] += s[t + st]; __syncthreads(); }
    if (t == 0) *flag = (s[0] > 64) ? 1 : 0;
}

// ---------------- tables ----------------------------------------------------
__launch_bounds__(256)
__global__ void tab_band_kernel(bf16_t* __restrict__ Ahi, bf16_t* __restrict__ Alo) {
    int m = blockIdx.x * 256 + threadIdx.x;
    int r = blockIdx.y;
    double v = 0.0;
    if (r < NF2) {
        int f  = P_LO + (r < NF ? r : r - NF);
        int ph = (f * m) & (SEQ - 1);
        double ang = (2.0 * DPI / SEQ) * (double)ph;
        v = (r < NF) ? cos(ang) : sin(ang);
    }
    bf16_t h = (bf16_t)(float)v;
    Ahi[(size_t)r * SEQ + m] = h;
    Alo[(size_t)r * SEQ + m] = (bf16_t)(float)(v - (double)(float)h);
}

__launch_bounds__(128)
__global__ void tab_inv_kernel(bf16_t* __restrict__ Gt) {
    int r = blockIdx.x * 128 + threadIdx.x;
    int n = blockIdx.y;
    float v = 0.f;
    if (r < NF2) {
        int f  = P_LO + (r < NF ? r : r - NF);
        int ph = (f * n) & (SEQ - 1);
        double ang = (2.0 * DPI / SEQ) * (double)ph;
        v = (float)((2.0 / SEQ) * ((r < NF) ? cos(ang) : sin(ang)));
    }
    Gt[(size_t)n * NFP + r] = (bf16_t)v;
}

// ---------------- normalize X: Xh[n][d] + transposed split XTh/XTl[b][d][n] -
__launch_bounds__(256)
__global__ void norm_x_kernel(const int* __restrict__ flag, const void* __restrict__ Xv,
                              bf16_t* __restrict__ Xh, bf16_t* __restrict__ XTh,
                              bf16_t* __restrict__ XTl) {
    int fl = *flag;
    __shared__ float T[64 * 65];
    int t = threadIdx.x;
    int R0 = blockIdx.y * 64, C0 = blockIdx.x * 64;
    int r = t >> 2;
    #pragma unroll
    for (int it = 0; it < 2; it++) {
        int c = (t & 3) * 8 + it * 32;
        float x[8];
        if (fl) {
            const float* p = (const float*)Xv + (size_t)(R0 + r) * HID + C0 + c;
            #pragma unroll
            for (int e = 0; e < 8; e++) x[e] = p[e];
        } else {
            const bf16_t* p = (const bf16_t*)Xv + (size_t)(R0 + r) * HID + C0 + c;
            #pragma unroll
            for (int e = 0; e < 8; e++) x[e] = (float)p[e];
        }
        v8bf h;
        #pragma unroll
        for (int e = 0; e < 8; e++) { h[e] = (bf16_t)x[e]; T[(r) * 65 + c + e] = x[e]; }
        *(v8bf*)&Xh[(size_t)(R0 + r) * HID + C0 + c] = h;
    }
    __syncthreads();
    int b  = blockIdx.y >> 5;
    int Rl = R0 - b * SEQ;
    int d  = t >> 2;
    #pragma unroll
    for (int it = 0; it < 2; it++) {
        int n = (t & 3) * 8 + it * 32;
        v8bf h, l;
        #pragma unroll
        for (int e = 0; e < 8; e++) {
            float x = T[(n + e) * 65 + d];
            bf16_t hh = (bf16_t)x;
            h[e] = hh; l[e] = (bf16_t)(x - (float)hh);
        }
        size_t off = ((size_t)b * HID + C0 + d) * SEQ + Rl + n;
        *(v8bf*)&XTh[off] = h;
        *(v8bf*)&XTl[off] = l;
    }
}

// ---------------- 128x128 dense NT GEMM + bias (m97-style) ------------------
// C[M,1024] = A[M,1024] @ Braw[1024,1024]^T + bias. A bf16 via GLDS; B raw
// (bf16 GLDS / f32 convert). outmode 1: f32 out when fl.
__launch_bounds__(256)
__global__ void gemm128_nt(const int* __restrict__ flag, const bf16_t* __restrict__ A,
                           const void* __restrict__ Braw, const void* __restrict__ biasraw,
                           void* __restrict__ Out, int outmode) {
    int fl = *flag;
    __shared__ __align__(16) bf16_t As[128 * 32];
    __shared__ __align__(16) bf16_t Bs[128 * 32];
    int t = threadIdx.x, wave = t >> 6, lane = t & 63;
    int lrow = lane & 15, quad = lane >> 4;
    int m0 = blockIdx.y * 128, n0 = blockIdx.x * 128;
    int wm = (wave >> 1) * 64, wn = (wave & 1) * 64;
    int grow = lane >> 2, gcol = (lane & 3) * 8;
    v4f acc[4][4] = {};
    for (int k0 = 0; k0 < HID; k0 += 32) {
        __syncthreads();
        GLDS(&A[(size_t)(m0 + wave * 32 + grow) * HID + k0 + gcol],      &As[(wave * 32) * 32]);
        GLDS(&A[(size_t)(m0 + wave * 32 + 16 + grow) * HID + k0 + gcol], &As[(wave * 32 + 16) * 32]);
        if (!fl) {
            const bf16_t* B = (const bf16_t*)Braw;
            GLDS(&B[(size_t)(n0 + wave * 32 + grow) * HID + k0 + gcol],      &Bs[(wave * 32) * 32]);
            GLDS(&B[(size_t)(n0 + wave * 32 + 16 + grow) * HID + k0 + gcol], &Bs[(wave * 32 + 16) * 32]);
        } else {
            const float* B = (const float*)Braw;
            #pragma unroll
            for (int i2 = 0; i2 < 2; i2++) {
                int row = (t >> 2) + 64 * i2, col = (t & 3) * 8;
                const float* p = &B[(size_t)(n0 + row) * HID + k0 + col];
                v8bf h;
                #pragma unroll
                for (int e = 0; e < 8; e++) h[e] = (bf16_t)p[e];
                *(v8bf*)&Bs[row * 32 + col] = h;
            }
        }
        __syncthreads();
        v8bf a[4], b[4];
        #pragma unroll
        for (int i = 0; i < 4; i++) a[i] = *(v8bf*)&As[(wm + i * 16 + lrow) * 32 + quad * 8];
        #pragma unroll
        for (int j = 0; j < 4; j++) b[j] = *(v8bf*)&Bs[(wn + j * 16 + lrow) * 32 + quad * 8];
        #pragma unroll
        for (int i = 0; i < 4; i++)
        #pragma unroll
        for (int j = 0; j < 4; j++) acc[i][j] = MFMA(a[i], b[j], acc[i][j]);
    }
    #pragma unroll
    for (int i = 0; i < 4; i++)
    #pragma unroll
    for (int j = 0; j < 4; j++) {
        int col = n0 + wn + 16 * j + lrow;
        float bvv = fl ? ((const float*)biasraw)[col] : (float)((const bf16_t*)biasraw)[col];
        #pragma unroll
        for (int rg = 0; rg < 4; rg++) {
            int row = m0 + wm + 16 * i + quad * 4 + rg;
            float v = acc[i][j][rg] + bvv;
            size_t off = (size_t)row * HID + col;
            if (outmode == 1 && fl) ((float*)Out)[off] = v;
            else ((bf16_t*)Out)[off] = (bf16_t)v;
        }
    }
}

// ---------------- band forward (64-tile, unchanged from R4) -----------------
__launch_bounds__(256)
__global__ void band_fwd(const bf16_t* __restrict__ Ahi, const bf16_t* __restrict__ Alo,
                         const bf16_t* __restrict__ XTh, const bf16_t* __restrict__ XTl,
                         bf16_t* __restrict__ Xfh, bf16_t* __restrict__ Xfl) {
    __shared__ __align__(16) bf16_t Ah[64 * 32], Al[64 * 32], Bh[64 * 32], Bl[64 * 32];
    int t = threadIdx.x, wave = t >> 6, lane = t & 63;
    int lrow = lane & 15, quad = lane >> 4;
    int m0 = blockIdx.y * 64, n0 = blockIdx.x * 64, b = blockIdx.z;
    int wm = (wave >> 1) * 32, wn = (wave & 1) * 32;
    int srow = t >> 2, scol = (t & 3) * 8;
    const bf16_t* bth = XTh + (size_t)b * HID * SEQ;
    const bf16_t* btl = XTl + (size_t)b * HID * SEQ;
    v4f acc[2][2] = {};
    for (int k0 = 0; k0 < SEQ; k0 += 32) {
        __syncthreads();
        GLDS(&Ahi[(size_t)(m0 + srow) * SEQ + k0 + scol], &Ah[srow * 32 + scol]);
        GLDS(&Alo[(size_t)(m0 + srow) * SEQ + k0 + scol], &Al[srow * 32 + scol]);
        GLDS(&bth[(size_t)(n0 + srow) * SEQ + k0 + scol], &Bh[srow * 32 + scol]);
        GLDS(&btl[(size_t)(n0 + srow) * SEQ + k0 + scol], &Bl[srow * 32 + scol]);
        __syncthreads();
        v8bf ah0 = *(v8bf*)&Ah[(wm + lrow) * 32 + quad * 8];
        v8bf ah1 = *(v8bf*)&Ah[(wm + 16 + lrow) * 32 + quad * 8];
        v8bf al0 = *(v8bf*)&Al[(wm + lrow) * 32 + quad * 8];
        v8bf al1 = *(v8bf*)&Al[(wm + 16 + lrow) * 32 + quad * 8];
        v8bf bh0 = *(v8bf*)&Bh[(wn + lrow) * 32 + quad * 8];
        v8bf bh1 = *(v8bf*)&Bh[(wn + 16 + lrow) * 32 + quad * 8];
        v8bf bl0 = *(v8bf*)&Bl[(wn + lrow) * 32 + quad * 8];
        v8bf bl1 = *(v8bf*)&Bl[(wn + 16 + lrow) * 32 + quad * 8];
        acc[0][0] = MFMA(ah0, bh0, acc[0][0]); acc[0][0] = MFMA(ah0, bl0, acc[0][0]); acc[0][0] = MFMA(al0, bh0, acc[0][0]);
        acc[0][1] = MFMA(ah0, bh1, acc[0][1]); acc[0][1] = MFMA(ah0, bl1, acc[0][1]); acc[0][1] = MFMA(al0, bh1, acc[0][1]);
        acc[1][0] = MFMA(ah1, bh0, acc[1][0]); acc[1][0] = MFMA(ah1, bl0, acc[1][0]); acc[1][0] = MFMA(al1, bh0, acc[1][0]);
        acc[1][1] = MFMA(ah1, bh1, acc[1][1]); acc[1][1] = MFMA(ah1, bl1, acc[1][1]); acc[1][1] = MFMA(al1, bh1, acc[1][1]);
    }
    bf16_t* oh = Xfh + (size_t)b * NFP * HID;
    bf16_t* ol = Xfl + (size_t)b * NFP * HID;
    #pragma unroll
    for (int i = 0; i < 2; i++)
    #pragma unroll
    for (int j = 0; j < 2; j++) {
        int col = n0 + wn + 16 * j + lrow;
        #pragma unroll
        for (int rg = 0; rg < 4; rg++) {
            int row = m0 + wm + 16 * i + quad * 4 + rg;
            float v = acc[i][j][rg];
            bf16_t h = (bf16_t)v;
            oh[(size_t)row * HID + col] = h;
            ol[(size_t)row * HID + col] = (bf16_t)(v - (float)h);
        }
    }
}

// ---------------- proj (64-tile; packed CT writes) --------------------------
template<bool QK>
__launch_bounds__(256)
__global__ void proj_f(const int* __restrict__ flag, const bf16_t* __restrict__ Xfh,
                       const bf16_t* __restrict__ Xfl, const void* __restrict__ Wraw,
                       bf16_t* __restrict__ Ch, bf16_t* __restrict__ Cl,
                       bf16_t* __restrict__ CT) {
    int fl = *flag;
    __shared__ __align__(16) bf16_t Ah[64 * 32], Al[64 * 32], Bh[64 * 32];
    __shared__ __align__(16) bf16_t Bl[QK ? 64 * 32 : 8];
    int t = threadIdx.x, wave = t >> 6, lane = t & 63;
    int lrow = lane & 15, quad = lane >> 4;
    int m0 = blockIdx.y * 64, n0 = blockIdx.x * 64;
    int wm = (wave >> 1) * 32, wn = (wave & 1) * 32;
    int srow = t >> 2, scol = (t & 3) * 8;
    const size_t zo = (size_t)blockIdx.z * NFP * HID;
    v4f acc[2][2] = {};
    for (int k0 = 0; k0 < HID; k0 += 32) {
        __syncthreads();
        GLDS(&Xfh[zo + (size_t)(m0 + srow) * HID + k0 + scol], &Ah[srow * 32 + scol]);
        GLDS(&Xfl[zo + (size_t)(m0 + srow) * HID + k0 + scol], &Al[srow * 32 + scol]);
        {
            float xb[8];
            if (fl) {
                const float* p = (const float*)Wraw + (size_t)(n0 + srow) * HID + k0 + scol;
                #pragma unroll
                for (int e = 0; e < 8; e++) xb[e] = p[e];
            } else {
                const bf16_t* p = (const bf16_t*)Wraw + (size_t)(n0 + srow) * HID + k0 + scol;
                #pragma unroll
                for (int e = 0; e < 8; e++) xb[e] = (float)p[e];
            }
            v8bf h, l;
            #pragma unroll
            for (int e = 0; e < 8; e++) {
                bf16_t hh = (bf16_t)xb[e];
                h[e] = hh; l[e] = (bf16_t)(xb[e] - (float)hh);
            }
            *(v8bf*)&Bh[srow * 32 + scol] = h;
            if constexpr (QK) *(v8bf*)&Bl[srow * 32 + scol] = l;
        }
        __syncthreads();
        v8bf ah0 = *(v8bf*)&Ah[(wm + lrow) * 32 + quad * 8];
        v8bf ah1 = *(v8bf*)&Ah[(wm + 16 + lrow) * 32 + quad * 8];
        v8bf al0 = *(v8bf*)&Al[(wm + lrow) * 32 + quad * 8];
        v8bf al1 = *(v8bf*)&Al[(wm + 16 + lrow) * 32 + quad * 8];
        v8bf bh0 = *(v8bf*)&Bh[(wn + lrow) * 32 + quad * 8];
        v8bf bh1 = *(v8bf*)&Bh[(wn + 16 + lrow) * 32 + quad * 8];
        acc[0][0] = MFMA(ah0, bh0, acc[0][0]); acc[0][0] = MFMA(al0, bh0, acc[0][0]);
        acc[0][1] = MFMA(ah0, bh1, acc[0][1]); acc[0][1] = MFMA(al0, bh1, acc[0][1]);
        acc[1][0] = MFMA(ah1, bh0, acc[1][0]); acc[1][0] = MFMA(al1, bh0, acc[1][0]);
        acc[1][1] = MFMA(ah1, bh1, acc[1][1]); acc[1][1] = MFMA(al1, bh1, acc[1][1]);
        if constexpr (QK) {
            v8bf bl0 = *(v8bf*)&Bl[(wn + lrow) * 32 + quad * 8];
            v8bf bl1 = *(v8bf*)&Bl[(wn + 16 + lrow) * 32 + quad * 8];
            acc[0][0] = MFMA(ah0, bl0, acc[0][0]);
            acc[0][1] = MFMA(ah0, bl1, acc[0][1]);
            acc[1][0] = MFMA(ah1, bl0, acc[1][0]);
            acc[1][1] = MFMA(ah1, bl1, acc[1][1]);
        }
    }
    #pragma unroll
    for (int i = 0; i < 2; i++)
    #pragma unroll
    for (int j = 0; j < 2; j++) {
        int col = n0 + wn + 16 * j + lrow;
        v4bf pk;
        #pragma unroll
        for (int rg = 0; rg < 4; rg++) {
            int row = m0 + wm + 16 * i + quad * 4 + rg;
            float v = acc[i][j][rg];
            bf16_t h = (bf16_t)v;
            pk[rg] = h;
            if constexpr (QK) {
                Ch[zo + (size_t)row * HID + col] = h;
                Cl[zo + (size_t)row * HID + col] = (bf16_t)(v - (float)h);
            }
        }
        *(v4bf*)&CT[zo + (size_t)col * NFP + m0 + wm + 16 * i + quad * 4] = pk;
    }
}

// ---------------- inverse, 128-tile: C = Gt[2048,640] @ BT[b][1024,640]^T ---
template<bool TRANS>   // TRANS: Out[b][d][n], else Out[b][n][d]
__launch_bounds__(256)
__global__ void inv128_f(const bf16_t* __restrict__ Gt, const bf16_t* __restrict__ BT,
                         bf16_t* __restrict__ Out) {
    __shared__ __align__(16) bf16_t As[128 * 32];
    __shared__ __align__(16) bf16_t Bs[128 * 32];
    int t = threadIdx.x, wave = t >> 6, lane = t & 63;
    int lrow = lane & 15, quad = lane >> 4;
    int m0 = blockIdx.y * 128, n0 = blockIdx.x * 128, b = blockIdx.z;
    int wm = (wave >> 1) * 64, wn = (wave & 1) * 64;
    int grow = lane >> 2, gcol = (lane & 3) * 8;
    const bf16_t* Bp = BT + (size_t)b * HID * NFP;
    v4f acc[4][4] = {};
    for (int k0 = 0; k0 < NFP; k0 += 32) {
        __syncthreads();
        GLDS(&Gt[(size_t)(m0 + wave * 32 + grow) * NFP + k0 + gcol],      &As[(wave * 32) * 32]);
        GLDS(&Gt[(size_t)(m0 + wave * 32 + 16 + grow) * NFP + k0 + gcol], &As[(wave * 32 + 16) * 32]);
        GLDS(&Bp[(size_t)(n0 + wave * 32 + grow) * NFP + k0 + gcol],      &Bs[(wave * 32) * 32]);
        GLDS(&Bp[(size_t)(n0 + wave * 32 + 16 + grow) * NFP + k0 + gcol], &Bs[(wave * 32 + 16) * 32]);
        __syncthreads();
        v8bf a[4], bfr[4];
        #pragma unroll
        for (int i = 0; i < 4; i++) a[i]   = *(v8bf*)&As[(wm + i * 16 + lrow) * 32 + quad * 8];
        #pragma unroll
        for (int j = 0; j < 4; j++) bfr[j] = *(v8bf*)&Bs[(wn + j * 16 + lrow) * 32 + quad * 8];
        #pragma unroll
        for (int i = 0; i < 4; i++)
        #pragma unroll
        for (int j = 0; j < 4; j++) acc[i][j] = MFMA(a[i], bfr[j], acc[i][j]);
    }
    #pragma unroll
    for (int i = 0; i < 4; i++)
    #pragma unroll
    for (int j = 0; j < 4; j++) {
        int col = n0 + wn + 16 * j + lrow;
        if constexpr (TRANS) {
            v4bf pk;
            #pragma unroll
            for (int rg = 0; rg < 4; rg++) pk[rg] = (bf16_t)acc[i][j][rg];
            *(v4bf*)&Out[((size_t)b * HID + col) * SEQ + m0 + wm + 16 * i + quad * 4] = pk;
        } else {
            #pragma unroll
            for (int rg = 0; rg < 4; rg++) {
                int row = m0 + wm + 16 * i + quad * 4 + rg;
                Out[(size_t)b * SEQ * HID + (size_t)row * HID + col] = (bf16_t)acc[i][j][rg];
            }
        }
    }
}

// ---------------- flash attention: S^T layout, packed P, V^T input ----------
__launch_bounds__(256)
__global__ void attn_kernel(const bf16_t* __restrict__ Qt, const bf16_t* __restrict__ Kt,
                            const bf16_t* __restrict__ VT, bf16_t* __restrict__ TO) {
    __shared__ __align__(16) bf16_t Ks[64 * 72];
    __shared__ __align__(16) bf16_t Vs[64 * 72];
    __shared__ __align__(16) bf16_t Ps[4 * 16 * 72];
    int t = threadIdx.x, wave = t >> 6, lane = t & 63;
    int lrow = lane & 15, quad = lane >> 4;
    int h = blockIdx.y, b = blockIdx.z;
    int q0 = (gridDim.x - 1 - blockIdx.x) * 64;    // heavy tiles dispatch first
    const size_t base = (size_t)b * SEQ * HID + (size_t)h * HD;
    const bf16_t* vb_ = VT + ((size_t)b * HID + h * HD) * SEQ;
    bf16_t* Pw = &Ps[wave * 16 * 72];

    int qrow = q0 + wave * 16 + lrow;
    v8bf qa0 = *(const v8bf*)&Qt[base + (size_t)qrow * HID + quad * 8];
    v8bf qa1 = *(const v8bf*)&Qt[base + (size_t)qrow * HID + 32 + quad * 8];

    v4f o[4] = {};
    float m_i = -1e30f, l_i = 0.f;       // state for q = q0 + wave*16 + lrow
    int srow = t >> 2;
    int qloc = wave * 16 + lrow;
    int nch = q0 / 64 + 1;
    for (int c = 0; c < nch; c++) {
        int kb = c * 64;
        bool masked = (kb == q0);
        __syncthreads();
        #pragma unroll
        for (int rep = 0; rep < 2; rep++) {
            int cc = (t & 3) * 8 + rep * 32;
            *(v8bf*)&Ks[srow * 72 + cc] = *(const v8bf*)&Kt[base + (size_t)(kb + srow) * HID + cc];
            *(v8bf*)&Vs[srow * 72 + cc] = *(const v8bf*)&vb_[(size_t)srow * SEQ + kb + cc];
        }
        __syncthreads();
        // S^T: A = K-frag (m=key), B = Q regs (n=q) -> C[key=quad*4+r][q=lrow]
        v4f s[4];
        #pragma unroll
        for (int ct = 0; ct < 4; ct++) {
            v8bf kA0 = *(v8bf*)&Ks[(ct * 16 + lrow) * 72 + quad * 8];
            v8bf kA1 = *(v8bf*)&Ks[(ct * 16 + lrow) * 72 + 32 + quad * 8];
            v4f z = {};
            z = MFMA(kA0, qa0, z);
            s[ct] = MFMA(kA1, qa1, z);
        }
        float sv[4][4];
        float mx = -1e30f;
        #pragma unroll
        for (int ct = 0; ct < 4; ct++)
        #pragma unroll
        for (int r = 0; r < 4; r++) {
            float x = s[ct][r] * 0.125f;
            if (masked && (ct * 16 + quad * 4 + r > qloc)) x = -1e30f;
            sv[ct][r] = x;
            mx = fmaxf(mx, x);
        }
        mx = fmaxf(mx, __shfl_xor(mx, 16));
        mx = fmaxf(mx, __shfl_xor(mx, 32));
        float mnew = fmaxf(m_i, mx);
        float alpha = __expf(m_i - mnew);
        m_i = mnew;
        float rs = 0.f;
        #pragma unroll
        for (int ct = 0; ct < 4; ct++)
        #pragma unroll
        for (int r = 0; r < 4; r++) { float p = __expf(sv[ct][r] - mnew); sv[ct][r] = p; rs += p; }
        rs += __shfl_xor(rs, 16);
        rs += __shfl_xor(rs, 32);
        l_i = l_i * alpha + rs;
        // rescale o (rows are q = quad*4+r; alpha lives at lane q in quad 0)
        #pragma unroll
        for (int r = 0; r < 4; r++) {
            float ar = __shfl(alpha, quad * 4 + r);
            #pragma unroll
            for (int dt = 0; dt < 4; dt++) o[dt][r] *= ar;
        }
        // P^T -> wave-local LDS in A-frag layout [q][key]; packed b64 writes
        #pragma unroll
        for (int ct = 0; ct < 4; ct++) {
            v4bf pk;
            #pragma unroll
            for (int r = 0; r < 4; r++) pk[r] = (bf16_t)sv[ct][r];
            *(v4bf*)&Pw[lrow * 72 + ct * 16 + quad * 4] = pk;
        }
        // wave-local: ds ops in-order per wave, lgkmcnt handles the dep
        v8bf pa0 = *(v8bf*)&Pw[lrow * 72 + quad * 8];
        v8bf pa1 = *(v8bf*)&Pw[lrow * 72 + 32 + quad * 8];
        #pragma unroll
        for (int dt = 0; dt < 4; dt++) {
            v8bf vb0 = *(v8bf*)&Vs[(dt * 16 + lrow) * 72 + quad * 8];
            v8bf vb1 = *(v8bf*)&Vs[(dt * 16 + lrow) * 72 + 32 + quad * 8];
            o[dt] = MFMA(pa0, vb0, o[dt]);
            o[dt] = MFMA(pa1, vb1, o[dt]);
        }
    }
    #pragma unroll
    for (int r = 0; r < 4; r++) {
        float lr = __shfl(l_i, quad * 4 + r);
        int qg = q0 + wave * 16 + quad * 4 + r;
        #pragma unroll
        for (int dt = 0; dt < 4; dt++)
            TO[base + (size_t)qg * HID + dt * 16 + lrow] = (bf16_t)(o[dt][r] / lr);
    }
}

// ---------------- freq branch ------------------------------------------------
__launch_bounds__(256)
__global__ void sfreq_kernel(const bf16_t* __restrict__ Qh, const bf16_t* __restrict__ Ql,
                             const bf16_t* __restrict__ Kh, const bf16_t* __restrict__ Kl,
                             float* __restrict__ Sre, float* __restrict__ Sim) {
    int f = blockIdx.x, b = blockIdx.y, t = threadIdx.x;
    const size_t oc = ((size_t)b * NFP + f) * HID;
    const size_t os = ((size_t)b * NFP + NF + f) * HID;
    float re = 0.f, im = 0.f;
    for (int d = t; d < HID; d += 256) {
        float cq = (float)Qh[oc + d] + (float)Ql[oc + d];
        float sq = (float)Qh[os + d] + (float)Ql[os + d];
        float ck = (float)Kh[oc + d] + (float)Kl[oc + d];
        float sk = (float)Kh[os + d] + (float)Kl[os + d];
        re += cq * ck + sq * sk;
        im += cq * sk - sq * ck;
    }
    #pragma unroll
    for (int msk = 1; msk < 64; msk <<= 1) { re += __shfl_xor(re, msk); im += __shfl_xor(im, msk); }
    __shared__ float rbuf[8];
    int wave = t >> 6, lane = t & 63;
    if (lane == 0) { rbuf[wave] = re; rbuf[4 + wave] = im; }
    __syncthreads();
    if (t == 0) {
        Sre[b * NF + f] = rbuf[0] + rbuf[1] + rbuf[2] + rbuf[3];
        Sim[b * NF + f] = rbuf[4] + rbuf[5] + rbuf[6] + rbuf[7];
    }
}

__launch_bounds__(256)
__global__ void rmean_kernel(const float* __restrict__ Sre, const float* __restrict__ Sim,
                             float* __restrict__ Rm) {
    int b = blockIdx.y;
    int n = blockIdx.x * 256 + threadIdx.x;
    __shared__ float sr[NF], si[NF];
    for (int i = threadIdx.x; i < NF; i += 256) { sr[i] = Sre[b * NF + i]; si[i] = Sim[b * NF + i]; }
    __syncthreads();
    float acc = 0.f;
    for (int r = 0; r < NF; r++) {
        int ph = ((P_LO + r) * n) & (SEQ - 1);
        float ang = (float)(2.0 * DPI / SEQ) * (float)ph;
        float sn, cs;
        sincosf(ang, &sn, &cs);
        acc += sr[r] * cs - si[r] * sn;
    }
    Rm[b * SEQ + n] = acc * (float)(2.0 / ((double)SEQ * (double)HID));
}

// ---------------- top-15: one wave per batch, register-resident, no barriers -
__launch_bounds__(64)
__global__ void topk_kernel(const float* __restrict__ Rm, int* __restrict__ Ti,
                            float* __restrict__ Tw) {
    int b = blockIdx.x, lane = threadIdx.x;
    float v[32];
    #pragma unroll
    for (int j = 0; j < 32; j++) v[j] = Rm[b * SEQ + j * 64 + lane];
    float selv[KTOP];
    int   seli[KTOP];
    for (int kk = 0; kk < KTOP; kk++) {
        float best = -INFINITY; int bi = lane;
        #pragma unroll
        for (int j = 0; j < 32; j++) {
            float x = v[j];
            if (x > best) { best = x; bi = j * 64 + lane; }   // ascending j: lowest idx on tie
        }
        #pragma unroll
        for (int off = 1; off < 64; off <<= 1) {
            float ov = __shfl_xor(best, off);
            int   oi = __shfl_xor(bi, off);
            if (ov > best || (ov == best && oi < bi)) { best = ov; bi = oi; }
        }
        selv[kk] = best; seli[kk] = bi;
        if (lane == (bi & 63)) v[bi >> 6] = -INFINITY;
    }
    float mx = selv[0];
    #pragma unroll
    for (int i = 1; i < KTOP; i++) mx = fmaxf(mx, selv[i]);
    float s = 0.f, e[KTOP];
    #pragma unroll
    for (int i = 0; i < KTOP; i++) { e[i] = __expf(selv[i] - mx); s += e[i]; }
    if (lane < KTOP) { Tw[b * KTOP + lane] = e[lane] / s; Ti[b * KTOP + lane] = seli[lane]; }
}

__launch_bounds__(256)
__global__ void combine_kernel(const bf16_t* __restrict__ TO, const bf16_t* __restrict__ V,
                               const int* __restrict__ Ti, const float* __restrict__ Tw,
                               bf16_t* __restrict__ Yc) {
    int b = blockIdx.z, n = blockIdx.y;
    int d = blockIdx.x * 256 + threadIdx.x;
    __shared__ int   ti[KTOP];
    __shared__ float tw[KTOP];
    if (threadIdx.x < KTOP) { ti[threadIdx.x] = Ti[b * KTOP + threadIdx.x]; tw[threadIdx.x] = Tw[b * KTOP + threadIdx.x]; }
    __syncthreads();
    float fo = 0.f;
    #pragma unroll
    for (int kk = 0; kk < KTOP; kk++) {
        int nn = (n - ti[kk] + SEQ) & (SEQ - 1);
        fo += tw[kk] * (float)V[((size_t)b * SEQ + nn) * HID + d];
    }
    size_t off = ((size_t)b * SEQ + n) * HID + d;
    Yc[off] = (bf16_t)(0.5f * (float)TO[off] + 0.5f * fo);
}

// ---------------- launcher ---------------------------------------------------
extern "C" void kernel_launch(void* const* d_in, const int* in_sizes, int n_in,
                              void* d_out, int out_size, void* d_ws, size_t ws_size,
                              hipStream_t stream) {
    (void)in_sizes; (void)n_in; (void)out_size; (void)ws_size;
    const void* X  = d_in[0];
    const void* Wq = d_in[2];
    const void* Wk = d_in[4];
    const void* Wv = d_in[6];
    const void* bv = d_in[7];
    const void* Wo = d_in[8];
    const void* bo = d_in[9];

    // ---- arena 41.5 MB, stream-ordered overlays (unchanged from R4, audited) ----
    const size_t SZ_X   = (size_t)BATCHN * SEQ * HID * 2;   // 8,388,608
    const size_t SZ_TAB = (size_t)NFP * SEQ * 2;            // 2,621,440
    const size_t SZ_F   = (size_t)BATCHN * NFP * HID * 2;   // 2,621,440
    char* w = (char*)d_ws;
    bf16_t* Xh  = (bf16_t*)(w);
    bf16_t* Xfh = (bf16_t*)(w);
    bf16_t* Xfl = (bf16_t*)(w + SZ_F);
    bf16_t* Qt  = (bf16_t*)(w);
    bf16_t* Yc  = (bf16_t*)(w);
    bf16_t* XTh = (bf16_t*)(w + SZ_X);
    bf16_t* Qfh = (bf16_t*)(w + SZ_X);
    bf16_t* Qfl = (bf16_t*)(w + SZ_X + SZ_F);
    bf16_t* Kfh = (bf16_t*)(w + SZ_X + 2 * SZ_F);
    bf16_t* Kt  = (bf16_t*)(w + SZ_X);
    bf16_t* XTl = (bf16_t*)(w + 2 * SZ_X);
    bf16_t* Kfl = (bf16_t*)(w + 2 * SZ_X);
    bf16_t* QfT = (bf16_t*)(w + 2 * SZ_X + SZ_F);
    bf16_t* KfT = (bf16_t*)(w + 2 * SZ_X + 2 * SZ_F);
    bf16_t* VT  = (bf16_t*)(w + 2 * SZ_X);
    bf16_t* Vm  = (bf16_t*)(w + 3 * SZ_X);
    bf16_t* Gt  = (bf16_t*)(w + 4 * SZ_X);
    bf16_t* Ahi = (bf16_t*)(w + 4 * SZ_X + SZ_TAB);
    bf16_t* Alo = (bf16_t*)(w + 4 * SZ_X + 2 * SZ_TAB);
    bf16_t* VfT = (bf16_t*)(w + 4 * SZ_X + SZ_TAB);
    char*  sm  = w + 4 * SZ_X + 3 * SZ_TAB;
    int*   flag = (int*)sm;
    float* Sre  = (float*)(sm + 256);
    float* Sim  = (float*)(sm + 256 + 4096);
    float* Rm   = (float*)(sm + 256 + 8192);
    int*   Ti   = (int*)  (sm + 256 + 8192 + 16384);
    float* Tw   = (float*)(sm + 256 + 8192 + 16384 + 256);
    bf16_t* TO  = (bf16_t*)d_out;   // d_out scratch (>= 8.39MB both dtypes)

    detect_kernel<<<1, 256, 0, stream>>>((const unsigned short*)X, (const unsigned short*)Wq, flag);
    norm_x_kernel<<<dim3(16, 64), 256, 0, stream>>>(flag, X, Xh, XTh, XTl);
    tab_band_kernel<<<dim3(SEQ / 256, NFP), 256, 0, stream>>>(Ahi, Alo);
    tab_inv_kernel<<<dim3(NFP / 128, SEQ), 128, 0, stream>>>(Gt);
    // V = X @ Wv^T + bv  (128-tile)
    gemm128_nt<<<dim3(8, 32), 256, 0, stream>>>(flag, Xh, Wv, bv, Vm, 0);
    // band DFT of X (3-pass split)
    band_fwd<<<dim3(16, NFP / 64, BATCHN), 256, 0, stream>>>(Ahi, Alo, XTh, XTl, Xfh, Xfl);
    // band coeffs: Q,K split (+transposed hi), V transposed hi only
    dim3 gP(16, NFP / 64, BATCHN);
    proj_f<true ><<<gP, 256, 0, stream>>>(flag, Xfh, Xfl, Wq, Qfh, Qfl, QfT);
    proj_f<true ><<<gP, 256, 0, stream>>>(flag, Xfh, Xfl, Wk, Kfh, Kfl, KfT);
    proj_f<false><<<gP, 256, 0, stream>>>(flag, Xfh, Xfl, Wv, nullptr, nullptr, VfT);
    // freq-branch stats (before overlays of Qfh/Qfl/Kfh/Kfl)
    sfreq_kernel<<<dim3(NF, BATCHN), 256, 0, stream>>>(Qfh, Qfl, Kfh, Kfl, Sre, Sim);
    rmean_kernel<<<dim3(SEQ / 256, BATCHN), 256, 0, stream>>>(Sre, Sim, Rm);
    topk_kernel<<<BATCHN, 64, 0, stream>>>(Rm, Ti, Tw);
    // inverse band transforms, 128-tile (order: Q, K, then V — overlay safety)
    dim3 gI(8, 16, BATCHN);
    inv128_f<false><<<gI, 256, 0, stream>>>(Gt, QfT, Qt);
    inv128_f<false><<<gI, 256, 0, stream>>>(Gt, KfT, Kt);
    inv128_f<true ><<<gI, 256, 0, stream>>>(Gt, VfT, VT);
    // attention -> TO (d_out scratch)
    attn_kernel<<<dim3(SEQ / 64, NHEADS, BATCHN), 256, 0, stream>>>(Qt, Kt, VT, TO);
    // combine -> Yc
    combine_kernel<<<dim3(HID / 256, SEQ, BATCHN), 256, 0, stream>>>(TO, Vm, Ti, Tw, Yc);
    // output projection (128-tile, flag-based output dtype)
    gemm128_nt<<<dim3(8, 32), 256, 0, stream>>>(flag, Yc, Wo, bo, d_out, 1);
}